// Round 14
// baseline (1428.974 us; speedup 1.0000x reference)
//
#include <hip/hip_runtime.h>
#include <cstdint>
#include <cstddef>

// ---------------------------------------------------------------------------
// Graphormer-ish encoder forward, MI355X (gfx950).
// Round 13: split-K=4 FFN2. FFN2 (K=3072, was 384 blocks = 1.5/CU with a
// 96-step serial K chain) now runs as 1536 blocks x K=768 into f32 partials
// + a deterministic fixed-order reduce (h += fb2 + sum of 4 partials).
// gemm2 gains K-stride + nsplit decode; other GEMMs unchanged (nsplit=1).
// ---------------------------------------------------------------------------

typedef __attribute__((ext_vector_type(8))) short bf16x8;
typedef __attribute__((ext_vector_type(4))) short bf16x4;
typedef __attribute__((ext_vector_type(4))) float f32x4;
typedef __attribute__((ext_vector_type(4))) unsigned int u32x4;

static constexpr int D    = 768;
static constexpr int H    = 12;
static constexpr int S    = 512;
static constexpr int NN   = 511;
static constexpr int B    = 8;
static constexpr int FFN  = 3072;
static constexpr int ROWS = B * S;   // 4096

__device__ __forceinline__ short f2b(float x) {
    union { float f; uint32_t u; } c; c.f = x;
    uint32_t r = (c.u + 0x7fffu + ((c.u >> 16) & 1u)) >> 16;  // RNE
    return (short)(uint16_t)r;
}
__device__ __forceinline__ float b2f_lo(uint32_t u) {
    union { uint32_t u; float f; } c; c.u = u << 16; return c.f;
}
__device__ __forceinline__ float b2f_hi(uint32_t u) {
    union { uint32_t u; float f; } c; c.u = u & 0xffff0000u; return c.f;
}
__device__ __forceinline__ float gelu_f(float x) {
    return 0.5f * x * (1.0f + erff(x * 0.7071067811865476f));
}
__device__ __forceinline__ void gload16(const void* g, void* l) {
    __builtin_amdgcn_global_load_lds(
        (const __attribute__((address_space(1))) void*)g,
        (__attribute__((address_space(3))) void*)l, 16, 0, 0);
}

// PV MFMA: 16x16x16 bf16 (builtin -> compiler handles MFMA hazards).
#if __has_builtin(__builtin_amdgcn_mfma_f32_16x16x16bf16_1k)
__device__ __forceinline__ f32x4 mfma16(bf16x4 a, bf16x4 b, f32x4 c) {
    return __builtin_amdgcn_mfma_f32_16x16x16bf16_1k(a, b, c, 0, 0, 0);
}
__device__ __forceinline__ void mfma16_fence(f32x4* o) { (void)o; }
#else
__device__ __forceinline__ f32x4 mfma16(bf16x4 a, bf16x4 b, f32x4 c) {
    asm volatile("s_nop 1\n\tv_mfma_f32_16x16x16_bf16 %0, %1, %2, %0"
                 : "+v"(c) : "v"(a), "v"(b));
    return c;
}
__device__ __forceinline__ void mfma16_fence(f32x4* o) {
    asm volatile("s_nop 7\n\ts_nop 7"
                 : "+v"(o[0]), "+v"(o[1]), "+v"(o[2]), "+v"(o[3]));
}
#endif

// ---------------------------------------------------------------------------
__global__ __launch_bounds__(256) void embed_kernel(
    const int* __restrict__ x, const float* __restrict__ emb,
    const float* __restrict__ gtok, float* __restrict__ h)
{
    int row = blockIdx.x;
    int b = row >> 9, s = row & (S - 1);
    const float* src = (s == 0) ? gtok : (emb + (size_t)x[b * NN + (s - 1)] * D);
    float* dst = h + (size_t)row * D;
    int t = threadIdx.x;
    dst[t]       = src[t];
    dst[t + 256] = src[t + 256];
    dst[t + 512] = src[t + 512];
}

// ---------------------------------------------------------------------------
__global__ void ac_kernel(const float* __restrict__ w1, const float* __restrict__ b1,
                          const float* __restrict__ w2, const float* __restrict__ b2,
                          float* __restrict__ ac)
{
    int h = threadIdx.x;
    if (h < H) {
        float a = 0.f, c = 0.f;
        for (int k = 0; k < 128; ++k) { a += w1[k] * w2[k * H + h]; c += b1[k] * w2[k * H + h]; }
        ac[h] = a; ac[16 + h] = c + b2[h];
    }
}

// ---------------------------------------------------------------------------
// Bias pack, [b][i][j] layout: pb[b,i,j] = u32( bf16(2*ab) | bf16(sp)<<16 )
// ---------------------------------------------------------------------------
__global__ __launch_bounds__(256) void bias_pack_kernel(
    const float* __restrict__ ab, const float* __restrict__ sp,
    uint32_t* __restrict__ pb)
{
    int row = blockIdx.x;                 // b*S + i
    int b = row >> 9, i = row & 511;
    const float* abr = ab + (size_t)row * S;
    const float* spr = sp + ((size_t)b * NN + (i - 1)) * NN;
    uint32_t* out = pb + (size_t)row * S;
    #pragma unroll
    for (int jt = 0; jt < 2; ++jt) {
        int j = jt * 256 + threadIdx.x;
        float a2 = 2.f * abr[j];
        float spv = (i > 0 && j > 0) ? spr[j - 1] : 0.f;
        out[j] = (uint32_t)(uint16_t)f2b(a2) | ((uint32_t)(uint16_t)f2b(spv) << 16);
    }
}

// ---------------------------------------------------------------------------
// Per-layer weight convert+transpose: f32 [R][C] -> bf16 [C][R].
// ---------------------------------------------------------------------------
__global__ __launch_bounds__(256) void wcvt_kernel(
    const float* __restrict__ wq, const float* __restrict__ wk,
    const float* __restrict__ wv, const float* __restrict__ wo,
    const float* __restrict__ f1, const float* __restrict__ f2,
    short* __restrict__ wqkvT, short* __restrict__ woT,
    short* __restrict__ f1T, short* __restrict__ f2T)
{
    int t = blockIdx.x;
    const float* in; short* out; int R, C, tr, tc;
    if (t < 432) {
        int which = t / 144, tt = t - which * 144;
        in = (which == 0) ? wq : ((which == 1) ? wk : wv);
        out = wqkvT + (size_t)which * 768 * 768;
        R = 768; C = 768; tr = tt / 12; tc = tt % 12;
    } else if (t < 576) {
        int tt = t - 432; in = wo; out = woT; R = 768; C = 768; tr = tt / 12; tc = tt % 12;
    } else if (t < 1152) {
        int tt = t - 576; in = f1; out = f1T; R = 768; C = 3072; tr = tt / 48; tc = tt % 48;
    } else {
        int tt = t - 1152; in = f2; out = f2T; R = 3072; C = 768; tr = tt / 12; tc = tt % 12;
    }
    int r0 = tr * 64, c0 = tc * 64;
    __shared__ short tile[64][65];
    int tid = threadIdx.x;
    #pragma unroll
    for (int i = 0; i < 16; ++i) {
        int e = i * 256 + tid; int r = e >> 6, c = e & 63;
        tile[r][c] = f2b(in[(size_t)(r0 + r) * C + c0 + c]);
    }
    __syncthreads();
    #pragma unroll
    for (int i = 0; i < 16; ++i) {
        int e = i * 256 + tid; int c = e >> 6, r = e & 63;
        out[(size_t)(c0 + c) * R + r0 + r] = tile[r][c];
    }
}

// ---------------------------------------------------------------------------
__global__ __launch_bounds__(256) void ln_kernel(
    const float* __restrict__ in, const float* __restrict__ sc,
    const float* __restrict__ bi, float* __restrict__ outF,
    short* __restrict__ outB)
{
    int row = blockIdx.x, t = threadIdx.x;
    const float* x = in + (size_t)row * D;
    float e0 = x[t], e1 = x[t + 256], e2 = x[t + 512];
    float s  = e0 + e1 + e2;
    float sq = e0 * e0 + e1 * e1 + e2 * e2;
    #pragma unroll
    for (int off = 1; off < 64; off <<= 1) { s += __shfl_xor(s, off); sq += __shfl_xor(sq, off); }
    __shared__ float red[8];
    int w = t >> 6, lane = t & 63;
    if (lane == 0) { red[w] = s; red[4 + w] = sq; }
    __syncthreads();
    s  = red[0] + red[1] + red[2] + red[3];
    sq = red[4] + red[5] + red[6] + red[7];
    float m   = s * (1.f / D);
    float inv = rsqrtf(sq * (1.f / D) - m * m + 1e-5f);
    float v0 = (e0 - m) * inv * sc[t]       + bi[t];
    float v1 = (e1 - m) * inv * sc[t + 256] + bi[t + 256];
    float v2 = (e2 - m) * inv * sc[t + 512] + bi[t + 512];
    if (outB) {
        short* o = outB + (size_t)row * D;
        o[t] = f2b(v0); o[t + 256] = f2b(v1); o[t + 512] = f2b(v2);
    } else {
        float* o = outF + (size_t)row * D;
        o[t] = v0; o[t + 256] = v1; o[t + 512] = v2;
    }
}

// ---------------------------------------------------------------------------
// FFN2 split-K reduce: h += fb2 + pt[0..3]  (fixed order -> deterministic)
// ---------------------------------------------------------------------------
__global__ __launch_bounds__(256) void ffn2_reduce_kernel(
    const float* __restrict__ pt, const float* __restrict__ fb2,
    float* __restrict__ h)
{
    const size_t SZ = (size_t)ROWS * D;
    int row = blockIdx.x, t = threadIdx.x;
    #pragma unroll
    for (int c = 0; c < 3; ++c) {
        int col = t + c * 256;
        size_t idx = (size_t)row * D + col;
        h[idx] += fb2[col] + pt[idx] + pt[SZ + idx] + pt[2 * SZ + idx] + pt[3 * SZ + idx];
    }
}

// ---------------------------------------------------------------------------
// 2-phase bf16 MFMA GEMM, BK=32, swizzle chunk ^= (r>>1)&3 both-sides.
// K = per-block K length; Kst = row stride of A/Wt; nsplit: split-K count
// (split sp handles K window [sp*K, (sp+1)*K), partials to outF + sp*M*nper).
// mode 0: f32 out + resid. 1: QKV bf16. 2: bf16 gelu. 3: f32 partial (no bias).
// ---------------------------------------------------------------------------
template<int BM>
__global__ __launch_bounds__(256) void gemm2(
    const short* __restrict__ A, const short* __restrict__ Wt,
    const float* __restrict__ Bb0, const float* __restrict__ Bb1, const float* __restrict__ Bb2,
    float* __restrict__ outF, const float* __restrict__ resid,
    short* __restrict__ outB,
    int K, int Kst, int nper, int gx, int nsplit, float alpha0, int mode)
{
    constexpr int MR = BM / 32;
    __shared__ __align__(16) short As[2][BM * 32];
    __shared__ __align__(16) short Bs[2][128 * 32];
    int tid  = threadIdx.x;
    int lane = tid & 63;
    int w    = tid >> 6;

    int nwg = gridDim.x;
    int bid = blockIdx.x;
    int sid = (bid & 7) * (nwg >> 3) + (bid >> 3);
    int per = nwg / nsplit;
    int sp  = sid / per;
    int rem = sid - sp * per;
    int row0 = (rem % gx) * BM;
    int n0   = (rem / gx) * 128;
    A  += (size_t)sp * K;                   // K-window offset (stride Kst)
    Wt += (size_t)sp * K;
    float* outFp = outF + (mode == 3 ? (size_t)sp * ROWS * nper : 0);

    int which = n0 / nper;
    int ncol0 = n0 - which * nper;
    const float* Bv = (which == 0) ? Bb0 : ((which == 1) ? Bb1 : Bb2);
    float alpha = (which == 0) ? alpha0 : 1.0f;

    int wr = (w >> 1) * (BM / 2);
    int wc = (w & 1) * 64;
    int fr = lane & 15;
    int q4 = lane >> 4;          // 0..3 (16B chunk within 64B row)

    f32x4 acc[MR][4] = {};

    auto stageA = [&](int buf, int k0) {
        #pragma unroll
        for (int ii = 0; ii < BM / 64; ++ii) {
            int U = ii * 256 + tid;          // 16B unit
            int r = U >> 2;
            int ch = (U & 3) ^ ((r >> 1) & 3);
            gload16(A + (size_t)(row0 + r) * Kst + k0 + ch * 8,
                    (char*)&As[buf][0] + ((size_t)ii * 256 + w * 64) * 16);
        }
    };
    auto stageB = [&](int buf, int k0) {
        #pragma unroll
        for (int ii = 0; ii < 2; ++ii) {
            int U = ii * 256 + tid;
            int r = U >> 2;
            int ch = (U & 3) ^ ((r >> 1) & 3);
            gload16(Wt + (size_t)(n0 + r) * Kst + k0 + ch * 8,
                    (char*)&Bs[buf][0] + ((size_t)ii * 256 + w * 64) * 16);
        }
    };
    auto compute = [&](int buf) {
        bf16x8 af[MR], bfr[4];
        #pragma unroll
        for (int m = 0; m < MR; ++m) {
            int r = wr + m * 16 + fr;
            af[m] = *(const bf16x8*)((const char*)&As[buf][0]
                    + (size_t)r * 64 + ((q4 ^ ((r >> 1) & 3)) * 16));
        }
        #pragma unroll
        for (int n = 0; n < 4; ++n) {
            int r = wc + n * 16 + fr;
            bfr[n] = *(const bf16x8*)((const char*)&Bs[buf][0]
                    + (size_t)r * 64 + ((q4 ^ ((r >> 1) & 3)) * 16));
        }
        #pragma unroll
        for (int m = 0; m < MR; ++m)
            #pragma unroll
            for (int n = 0; n < 4; ++n)
                acc[m][n] = __builtin_amdgcn_mfma_f32_16x16x32_bf16(af[m], bfr[n], acc[m][n], 0, 0, 0);
    };

    int nt = K >> 5;
    stageA(0, 0); stageB(0, 0);
    __syncthreads();
    int cur = 0;
    for (int t = 1; t < nt; ++t) {
        stageA(cur ^ 1, t * 32);
        stageB(cur ^ 1, t * 32);
        compute(cur);
        __syncthreads();
        cur ^= 1;
    }
    compute(cur);

    int rr = q4 * 4;
    if (mode == 3) {
        #pragma unroll
        for (int m = 0; m < MR; ++m)
            #pragma unroll
            for (int n = 0; n < 4; ++n) {
                int col = ncol0 + wc + n * 16 + fr;
                #pragma unroll
                for (int ri = 0; ri < 4; ++ri) {
                    int row = row0 + wr + m * 16 + rr + ri;
                    outFp[(size_t)row * nper + col] = acc[m][n][ri];
                }
            }
        return;
    }
    if (mode == 1) {
        short* base = outB + (size_t)which * ROWS * D;
        #pragma unroll
        for (int m = 0; m < MR; ++m) {
            int rowb = row0 + wr + m * 16 + rr;
            int b2 = rowb >> 9, s0 = rowb & 511;
            #pragma unroll
            for (int n = 0; n < 4; ++n) {
                int col = ncol0 + wc + n * 16 + fr;
                int h2 = col >> 6, d2 = col & 63;
                float bv = Bv[col];
                if (which == 2) {
                    bf16x4 pk;
                    #pragma unroll
                    for (int ri = 0; ri < 4; ++ri) pk[ri] = f2b(acc[m][n][ri] + bv);
                    *(bf16x4*)&base[(((size_t)b2 * H + h2) * 64 + d2) * 512 + s0] = pk;
                } else {
                    #pragma unroll
                    for (int ri = 0; ri < 4; ++ri)
                        base[(((size_t)b2 * H + h2) * 512 + (s0 + ri)) * 64 + d2] =
                            f2b((acc[m][n][ri] + bv) * alpha);
                }
            }
        }
        return;
    }

    #pragma unroll
    for (int m = 0; m < MR; ++m) {
        #pragma unroll
        for (int n = 0; n < 4; ++n) {
            int col  = ncol0 + wc + n * 16 + fr;
            float bv = Bv[col];
            #pragma unroll
            for (int ri = 0; ri < 4; ++ri) {
                int row = row0 + wr + m * 16 + rr + ri;
                size_t idx = (size_t)row * nper + col;
                float val = acc[m][n][ri] + bv;
                if (mode == 2) {
                    outB[idx] = f2b(gelu_f(val));
                } else {
                    outF[idx] = val + resid[idx];
                }
            }
        }
    }
}

// ---------------------------------------------------------------------------
// LDS-staged online-softmax attention (round-10, verified).
// ---------------------------------------------------------------------------
__global__ __launch_bounds__(256) void attn_kernel(
    const short* __restrict__ qb, const short* __restrict__ kbuf,
    const short* __restrict__ vtb,
    const uint32_t* __restrict__ pb,
    const float* __restrict__ vd, const float* __restrict__ ac,
    short* __restrict__ o)
{
    __shared__ __align__(16) short Ks[2][128 * 64];
    __shared__ __align__(16) short Vs[2][64 * 128];
    int tid = threadIdx.x, lane = tid & 63, w = tid >> 6;
    int bid = blockIdx.x;
    int b    = bid & 7;
    int qblk = (bid >> 3) & 7;
    int hh   = bid >> 6;
    int fr = lane & 15, g16 = lane >> 4;
    int kb8 = g16 * 8, rr = g16 * 4;
    int i0 = qblk * 64 + w * 16;
    int i  = i0 + fr;

    const short* qp = qb   + ((size_t)(b * H + hh) * S) * 64;
    const short* kp = kbuf + ((size_t)(b * H + hh) * S) * 64;
    const short* vp = vtb  + ((size_t)(b * H + hh) * 64) * S;

    bf16x8 aq0 = *(const bf16x8*)&qp[(i0 + fr) * 64 + kb8];
    bf16x8 aq1 = *(const bf16x8*)&qp[(i0 + fr) * 64 + 32 + kb8];

    float Ah = ac[hh], Ch = ac[16 + hh], th = vd[hh];
    const uint32_t* pbb = pb + (size_t)b * S * S + (size_t)i * S;

    auto stageK = [&](int buf, int j0) {
        #pragma unroll
        for (int ii = 0; ii < 4; ++ii) {
            int U = ii * 256 + tid;
            int r = U >> 3;
            int ch = (U & 7) ^ (r & 7);
            gload16(kp + (size_t)(j0 + r) * 64 + ch * 8,
                    (char*)&Ks[buf][0] + ((size_t)ii * 256 + w * 64) * 16);
        }
    };
    auto stageV = [&](int buf, int j0) {
        #pragma unroll
        for (int ii = 0; ii < 4; ++ii) {
            int U = ii * 256 + tid;
            int d = U >> 4;
            int s8 = (2 * (U & 15)) ^ (d & 14);
            gload16(vp + (size_t)d * S + j0 + s8 * 4,
                    (char*)&Vs[buf][0] + ((size_t)ii * 256 + w * 64) * 16);
        }
    };

    float m_run = -3.0e38f, l_run = 0.f;
    f32x4 oacc[4] = {};

    stageK(0, 0);
    stageV(0, 0);
    __syncthreads();
    int buf = 0;
    #pragma unroll 1
    for (int t = 0; t < 4; ++t) {
        if (t < 3) { stageK(buf ^ 1, (t + 1) * 128); stageV(buf ^ 1, (t + 1) * 128); }
        f32x4 s[8];
        #pragma unroll
        for (int jt = 0; jt < 8; ++jt) {
            int jb = t * 8 + jt;
            u32x4 u = *(const u32x4*)&pbb[jb * 16 + rr];
            f32x4 c;
            #pragma unroll
            for (int ri = 0; ri < 4; ++ri) {
                int j = jb * 16 + rr + ri;
                float bias = b2f_lo(u[ri]);
                if (i > 0 && j > 0) bias += b2f_hi(u[ri]) * Ah + Ch;
                if (i == 0 || j == 0) bias += th;
                c[ri] = bias;
            }
            int r = jt * 16 + fr;
            const char* krow = (const char*)&Ks[buf][0] + r * 128;
            bf16x8 kf0 = *(const bf16x8*)(krow + ((g16 ^ (r & 7)) * 16));
            bf16x8 kf1 = *(const bf16x8*)(krow + (((g16 + 4) ^ (r & 7)) * 16));
            c = __builtin_amdgcn_mfma_f32_16x16x32_bf16(kf0, aq0, c, 0, 0, 0);
            s[jt] = __builtin_amdgcn_mfma_f32_16x16x32_bf16(kf1, aq1, c, 0, 0, 0);
        }
        float tm = s[0][0];
        #pragma unroll
        for (int jt = 0; jt < 8; ++jt)
            #pragma unroll
            for (int ri = 0; ri < 4; ++ri) tm = fmaxf(tm, s[jt][ri]);
        tm = fmaxf(tm, __shfl_xor(tm, 16));
        tm = fmaxf(tm, __shfl_xor(tm, 32));
        float mnew = fmaxf(m_run, tm);
        float scale = __expf(m_run - mnew);
        l_run *= scale;
        #pragma unroll
        for (int ri = 0; ri < 4; ++ri) {
            float scr = __shfl(scale, rr + ri);
            #pragma unroll
            for (int dt = 0; dt < 4; ++dt) oacc[dt][ri] *= scr;
        }
        #pragma unroll
        for (int jt = 0; jt < 8; ++jt)
            #pragma unroll
            for (int ri = 0; ri < 4; ++ri) {
                float p = __expf(s[jt][ri] - mnew);
                s[jt][ri] = p;
                l_run += p;
            }
        #pragma unroll
        for (int jt = 0; jt < 8; ++jt) {
            bf16x4 pa;
            #pragma unroll
            for (int ri = 0; ri < 4; ++ri) pa[ri] = f2b(s[jt][ri]);
            #pragma unroll
            for (int dt = 0; dt < 4; ++dt) {
                int d = dt * 16 + fr;
                const char* vrow = (const char*)&Vs[buf][0] + d * 256;
                bf16x4 vb = *(const bf16x4*)(vrow + (((jt * 4 + g16) ^ (d & 14)) * 8));
                oacc[dt] = mfma16(pa, vb, oacc[dt]);
            }
        }
        m_run = mnew;
        __syncthreads();
        buf ^= 1;
    }
    mfma16_fence(oacc);

    l_run += __shfl_xor(l_run, 16);
    l_run += __shfl_xor(l_run, 32);
    float invl = 1.f / l_run;
    #pragma unroll
    for (int ri = 0; ri < 4; ++ri) {
        float ivr = __shfl(invl, rr + ri);
        #pragma unroll
        for (int dt = 0; dt < 4; ++dt)
            o[((size_t)(b * S + i0 + rr + ri) * H + hh) * 64 + dt * 16 + fr] =
                f2b(oacc[dt][ri] * ivr);
    }
}

// ---------------------------------------------------------------------------
extern "C" void kernel_launch(void* const* d_in, const int* in_sizes, int n_in,
                              void* d_out, int out_size, void* d_ws, size_t ws_size,
                              hipStream_t stream)
{
    const float* attn_bias   = (const float*)d_in[0];
    const float* spatial_pos = (const float*)d_in[1];
    const int*   xx          = (const int*)d_in[2];
    const float* node_emb    = (const float*)d_in[3];
    const float* graph_token = (const float*)d_in[4];
    const float* virt_dist   = (const float*)d_in[5];
    const float* sp_w1 = (const float*)d_in[6];
    const float* sp_b1 = (const float*)d_in[7];
    const float* sp_w2 = (const float*)d_in[8];
    const float* sp_b2 = (const float*)d_in[9];
    const float* ln1_s = (const float*)d_in[10];
    const float* ln1_b = (const float*)d_in[11];
    const float* wq = (const float*)d_in[12];
    const float* bq = (const float*)d_in[13];
    const float* wk = (const float*)d_in[14];
    const float* bk = (const float*)d_in[15];
    const float* wv = (const float*)d_in[16];
    const float* bv = (const float*)d_in[17];
    const float* wo = (const float*)d_in[18];
    const float* bo = (const float*)d_in[19];
    const float* ln2_s = (const float*)d_in[20];
    const float* ln2_b = (const float*)d_in[21];
    const float* fw1 = (const float*)d_in[22];
    const float* fb1 = (const float*)d_in[23];
    const float* fw2 = (const float*)d_in[24];
    const float* fb2 = (const float*)d_in[25];
    const float* fln_s = (const float*)d_in[26];
    const float* fln_b = (const float*)d_in[27];

    float* wsf = (float*)d_ws;
    const size_t SZ = (size_t)ROWS * D;        // 3,145,728
    float* h   = wsf;                          // f32 [ROWS][D]
    float* acb = wsf + SZ;                     // A[12],C[12]
    short* s16 = (short*)(wsf + SZ + 64);
    short* yob = s16;                          // bf16 [ROWS][D]
    short* g16b = s16 + SZ;                    // bf16 [ROWS][FFN]
    short* bfq = g16b + (size_t)ROWS * FFN;    // 3 x bf16 [ROWS*D]
    short* wqkvT = bfq + 3 * SZ;               // [2304][768]
    short* woT   = wqkvT + 2304 * 768;         // [768][768]
    short* f1T   = woT + 768 * 768;            // [3072][768]
    short* f2T   = f1T + (size_t)3072 * 768;   // [768][3072]
    uint32_t* pbias = (uint32_t*)(f2T + (size_t)768 * 3072);  // [B][S][S] u32
    float* ptb = (float*)(pbias + (size_t)B * S * S);         // [4][ROWS][768] f32

    embed_kernel<<<ROWS, 256, 0, stream>>>(xx, node_emb, graph_token, h);
    ac_kernel<<<1, 64, 0, stream>>>(sp_w1, sp_b1, sp_w2, sp_b2, acb);
    bias_pack_kernel<<<ROWS, 256, 0, stream>>>(attn_bias, spatial_pos, pbias);

    for (int l = 0; l < 6; ++l) {
        wcvt_kernel<<<1728, 256, 0, stream>>>(
            wq + (size_t)l * D * D, wk + (size_t)l * D * D, wv + (size_t)l * D * D,
            wo + (size_t)l * D * D, fw1 + (size_t)l * D * FFN, fw2 + (size_t)l * FFN * D,
            wqkvT, woT, f1T, f2T);
        ln_kernel<<<ROWS, 256, 0, stream>>>(h, ln1_s + l * D, ln1_b + l * D, nullptr, yob);
        gemm2<128><<<576, 256, 0, stream>>>(
            yob, wqkvT, bq + l * D, bk + l * D, bv + l * D,
            nullptr, nullptr, bfq, D, D, D, 32, 1, 0.125f, 1);
        attn_kernel<<<B * H * 8, 256, 0, stream>>>(
            bfq, bfq + SZ, bfq + 2 * SZ, pbias, virt_dist, acb, yob);
        gemm2<64><<<384, 256, 0, stream>>>(
            yob, woT, bo + l * D, nullptr, nullptr,
            h, h, nullptr, D, D, D, 64, 1, 1.0f, 0);
        ln_kernel<<<ROWS, 256, 0, stream>>>(h, ln2_s + l * D, ln2_b + l * D, nullptr, yob);
        gemm2<128><<<768, 256, 0, stream>>>(
            yob, f1T, fb1 + l * FFN, nullptr, nullptr,
            nullptr, nullptr, g16b, D, D, FFN, 32, 1, 1.0f, 2);
        // FFN2 split-K=4: 1536 blocks, each K=768 window -> f32 partials
        gemm2<64><<<1536, 256, 0, stream>>>(
            g16b, f2T, nullptr, nullptr, nullptr,
            ptb, nullptr, nullptr, 768, FFN, D, 64, 4, 1.0f, 3);
        ffn2_reduce_kernel<<<ROWS, 256, 0, stream>>>(ptb, fb2 + l * D, h);
    }
    ln_kernel<<<ROWS, 256, 0, stream>>>(h, fln_s, fln_b, (float*)d_out, nullptr);
}

// Round 15
// 1227.497 us; speedup vs baseline: 1.1641x; 1.1641x over previous
//
#include <hip/hip_runtime.h>
#include <cstdint>
#include <cstddef>

// ---------------------------------------------------------------------------
// Graphormer-ish encoder forward, MI355X (gfx950).
// Round 14: (a) revert round-13 split-K FFN2 (regression). (b) GEMM pipeline
// depth 2: 3 LDS buffers, counted s_waitcnt vmcnt(NL) + raw s_barrier (no
// vmcnt(0) drain), stage(t+2) after the barrier. Covers ~2 K-step durations
// of HBM latency that the 2-phase __syncthreads drain exposed every step.
// ---------------------------------------------------------------------------

typedef __attribute__((ext_vector_type(8))) short bf16x8;
typedef __attribute__((ext_vector_type(4))) short bf16x4;
typedef __attribute__((ext_vector_type(4))) float f32x4;
typedef __attribute__((ext_vector_type(4))) unsigned int u32x4;

static constexpr int D    = 768;
static constexpr int H    = 12;
static constexpr int S    = 512;
static constexpr int NN   = 511;
static constexpr int B    = 8;
static constexpr int FFN  = 3072;
static constexpr int ROWS = B * S;   // 4096

__device__ __forceinline__ short f2b(float x) {
    union { float f; uint32_t u; } c; c.f = x;
    uint32_t r = (c.u + 0x7fffu + ((c.u >> 16) & 1u)) >> 16;  // RNE
    return (short)(uint16_t)r;
}
__device__ __forceinline__ float b2f_lo(uint32_t u) {
    union { uint32_t u; float f; } c; c.u = u << 16; return c.f;
}
__device__ __forceinline__ float b2f_hi(uint32_t u) {
    union { uint32_t u; float f; } c; c.u = u & 0xffff0000u; return c.f;
}
__device__ __forceinline__ float gelu_f(float x) {
    return 0.5f * x * (1.0f + erff(x * 0.7071067811865476f));
}
__device__ __forceinline__ void gload16(const void* g, void* l) {
    __builtin_amdgcn_global_load_lds(
        (const __attribute__((address_space(1))) void*)g,
        (__attribute__((address_space(3))) void*)l, 16, 0, 0);
}

// PV MFMA: 16x16x16 bf16 (builtin -> compiler handles MFMA hazards).
#if __has_builtin(__builtin_amdgcn_mfma_f32_16x16x16bf16_1k)
__device__ __forceinline__ f32x4 mfma16(bf16x4 a, bf16x4 b, f32x4 c) {
    return __builtin_amdgcn_mfma_f32_16x16x16bf16_1k(a, b, c, 0, 0, 0);
}
__device__ __forceinline__ void mfma16_fence(f32x4* o) { (void)o; }
#else
__device__ __forceinline__ f32x4 mfma16(bf16x4 a, bf16x4 b, f32x4 c) {
    asm volatile("s_nop 1\n\tv_mfma_f32_16x16x16_bf16 %0, %1, %2, %0"
                 : "+v"(c) : "v"(a), "v"(b));
    return c;
}
__device__ __forceinline__ void mfma16_fence(f32x4* o) {
    asm volatile("s_nop 7\n\ts_nop 7"
                 : "+v"(o[0]), "+v"(o[1]), "+v"(o[2]), "+v"(o[3]));
}
#endif

// ---------------------------------------------------------------------------
__global__ __launch_bounds__(256) void embed_kernel(
    const int* __restrict__ x, const float* __restrict__ emb,
    const float* __restrict__ gtok, float* __restrict__ h)
{
    int row = blockIdx.x;
    int b = row >> 9, s = row & (S - 1);
    const float* src = (s == 0) ? gtok : (emb + (size_t)x[b * NN + (s - 1)] * D);
    float* dst = h + (size_t)row * D;
    int t = threadIdx.x;
    dst[t]       = src[t];
    dst[t + 256] = src[t + 256];
    dst[t + 512] = src[t + 512];
}

// ---------------------------------------------------------------------------
__global__ void ac_kernel(const float* __restrict__ w1, const float* __restrict__ b1,
                          const float* __restrict__ w2, const float* __restrict__ b2,
                          float* __restrict__ ac)
{
    int h = threadIdx.x;
    if (h < H) {
        float a = 0.f, c = 0.f;
        for (int k = 0; k < 128; ++k) { a += w1[k] * w2[k * H + h]; c += b1[k] * w2[k * H + h]; }
        ac[h] = a; ac[16 + h] = c + b2[h];
    }
}

// ---------------------------------------------------------------------------
// Bias pack, [b][i][j] layout: pb[b,i,j] = u32( bf16(2*ab) | bf16(sp)<<16 )
// ---------------------------------------------------------------------------
__global__ __launch_bounds__(256) void bias_pack_kernel(
    const float* __restrict__ ab, const float* __restrict__ sp,
    uint32_t* __restrict__ pb)
{
    int row = blockIdx.x;                 // b*S + i
    int b = row >> 9, i = row & 511;
    const float* abr = ab + (size_t)row * S;
    const float* spr = sp + ((size_t)b * NN + (i - 1)) * NN;
    uint32_t* out = pb + (size_t)row * S;
    #pragma unroll
    for (int jt = 0; jt < 2; ++jt) {
        int j = jt * 256 + threadIdx.x;
        float a2 = 2.f * abr[j];
        float spv = (i > 0 && j > 0) ? spr[j - 1] : 0.f;
        out[j] = (uint32_t)(uint16_t)f2b(a2) | ((uint32_t)(uint16_t)f2b(spv) << 16);
    }
}

// ---------------------------------------------------------------------------
// Per-layer weight convert+transpose: f32 [R][C] -> bf16 [C][R].
// ---------------------------------------------------------------------------
__global__ __launch_bounds__(256) void wcvt_kernel(
    const float* __restrict__ wq, const float* __restrict__ wk,
    const float* __restrict__ wv, const float* __restrict__ wo,
    const float* __restrict__ f1, const float* __restrict__ f2,
    short* __restrict__ wqkvT, short* __restrict__ woT,
    short* __restrict__ f1T, short* __restrict__ f2T)
{
    int t = blockIdx.x;
    const float* in; short* out; int R, C, tr, tc;
    if (t < 432) {
        int which = t / 144, tt = t - which * 144;
        in = (which == 0) ? wq : ((which == 1) ? wk : wv);
        out = wqkvT + (size_t)which * 768 * 768;
        R = 768; C = 768; tr = tt / 12; tc = tt % 12;
    } else if (t < 576) {
        int tt = t - 432; in = wo; out = woT; R = 768; C = 768; tr = tt / 12; tc = tt % 12;
    } else if (t < 1152) {
        int tt = t - 576; in = f1; out = f1T; R = 768; C = 3072; tr = tt / 48; tc = tt % 48;
    } else {
        int tt = t - 1152; in = f2; out = f2T; R = 3072; C = 768; tr = tt / 12; tc = tt % 12;
    }
    int r0 = tr * 64, c0 = tc * 64;
    __shared__ short tile[64][65];
    int tid = threadIdx.x;
    #pragma unroll
    for (int i = 0; i < 16; ++i) {
        int e = i * 256 + tid; int r = e >> 6, c = e & 63;
        tile[r][c] = f2b(in[(size_t)(r0 + r) * C + c0 + c]);
    }
    __syncthreads();
    #pragma unroll
    for (int i = 0; i < 16; ++i) {
        int e = i * 256 + tid; int c = e >> 6, r = e & 63;
        out[(size_t)(c0 + c) * R + r0 + r] = tile[r][c];
    }
}

// ---------------------------------------------------------------------------
__global__ __launch_bounds__(256) void ln_kernel(
    const float* __restrict__ in, const float* __restrict__ sc,
    const float* __restrict__ bi, float* __restrict__ outF,
    short* __restrict__ outB)
{
    int row = blockIdx.x, t = threadIdx.x;
    const float* x = in + (size_t)row * D;
    float e0 = x[t], e1 = x[t + 256], e2 = x[t + 512];
    float s  = e0 + e1 + e2;
    float sq = e0 * e0 + e1 * e1 + e2 * e2;
    #pragma unroll
    for (int off = 1; off < 64; off <<= 1) { s += __shfl_xor(s, off); sq += __shfl_xor(sq, off); }
    __shared__ float red[8];
    int w = t >> 6, lane = t & 63;
    if (lane == 0) { red[w] = s; red[4 + w] = sq; }
    __syncthreads();
    s  = red[0] + red[1] + red[2] + red[3];
    sq = red[4] + red[5] + red[6] + red[7];
    float m   = s * (1.f / D);
    float inv = rsqrtf(sq * (1.f / D) - m * m + 1e-5f);
    float v0 = (e0 - m) * inv * sc[t]       + bi[t];
    float v1 = (e1 - m) * inv * sc[t + 256] + bi[t + 256];
    float v2 = (e2 - m) * inv * sc[t + 512] + bi[t + 512];
    if (outB) {
        short* o = outB + (size_t)row * D;
        o[t] = f2b(v0); o[t + 256] = f2b(v1); o[t + 512] = f2b(v2);
    } else {
        float* o = outF + (size_t)row * D;
        o[t] = v0; o[t + 256] = v1; o[t + 512] = v2;
    }
}

// ---------------------------------------------------------------------------
// bf16 MFMA GEMM, BK=32, swizzle chunk ^= (r>>1)&3 both-sides. Depth-2
// pipeline: 3 LDS buffers; per step `s_waitcnt vmcnt(NL)` (tile t landed,
// tile t+1 in flight) + raw s_barrier (no drain), then stage(t+2), then
// compute(t). Last step peeled with vmcnt(0). NL = per-thread loads/tile.
// ---------------------------------------------------------------------------
template<int BM>
__global__ __launch_bounds__(256) void gemm2(
    const short* __restrict__ A, const short* __restrict__ Wt,
    const float* __restrict__ Bb0, const float* __restrict__ Bb1, const float* __restrict__ Bb2,
    float* __restrict__ outF, const float* __restrict__ resid,
    short* __restrict__ outB,
    int K, int nper, int gx, float alpha0, int mode)
{
    constexpr int MR = BM / 32;
    constexpr int NL = BM / 64 + 2;          // per-thread global_load_lds per tile
    __shared__ __align__(16) short As[3][BM * 32];
    __shared__ __align__(16) short Bs[3][128 * 32];
    int tid  = threadIdx.x;
    int lane = tid & 63;
    int w    = tid >> 6;

    int nwg = gridDim.x;
    int bid = blockIdx.x;
    int sid = (bid & 7) * (nwg >> 3) + (bid >> 3);
    int row0 = (sid % gx) * BM;
    int n0   = (sid / gx) * 128;

    int which = n0 / nper;
    int ncol0 = n0 - which * nper;
    const float* Bv = (which == 0) ? Bb0 : ((which == 1) ? Bb1 : Bb2);
    float alpha = (which == 0) ? alpha0 : 1.0f;

    int wr = (w >> 1) * (BM / 2);
    int wc = (w & 1) * 64;
    int fr = lane & 15;
    int q4 = lane >> 4;          // 0..3 (16B chunk within 64B row)

    f32x4 acc[MR][4] = {};

    auto stageA = [&](int buf, int k0) {
        #pragma unroll
        for (int ii = 0; ii < BM / 64; ++ii) {
            int U = ii * 256 + tid;          // 16B unit
            int r = U >> 2;
            int ch = (U & 3) ^ ((r >> 1) & 3);
            gload16(A + (size_t)(row0 + r) * K + k0 + ch * 8,
                    (char*)&As[buf][0] + ((size_t)ii * 256 + w * 64) * 16);
        }
    };
    auto stageB = [&](int buf, int k0) {
        #pragma unroll
        for (int ii = 0; ii < 2; ++ii) {
            int U = ii * 256 + tid;
            int r = U >> 2;
            int ch = (U & 3) ^ ((r >> 1) & 3);
            gload16(Wt + (size_t)(n0 + r) * K + k0 + ch * 8,
                    (char*)&Bs[buf][0] + ((size_t)ii * 256 + w * 64) * 16);
        }
    };
    auto compute = [&](int buf) {
        bf16x8 af[MR], bfr[4];
        #pragma unroll
        for (int m = 0; m < MR; ++m) {
            int r = wr + m * 16 + fr;
            af[m] = *(const bf16x8*)((const char*)&As[buf][0]
                    + (size_t)r * 64 + ((q4 ^ ((r >> 1) & 3)) * 16));
        }
        #pragma unroll
        for (int n = 0; n < 4; ++n) {
            int r = wc + n * 16 + fr;
            bfr[n] = *(const bf16x8*)((const char*)&Bs[buf][0]
                    + (size_t)r * 64 + ((q4 ^ ((r >> 1) & 3)) * 16));
        }
        #pragma unroll
        for (int m = 0; m < MR; ++m)
            #pragma unroll
            for (int n = 0; n < 4; ++n)
                acc[m][n] = __builtin_amdgcn_mfma_f32_16x16x32_bf16(af[m], bfr[n], acc[m][n], 0, 0, 0);
    };

    int nt = K >> 5;                          // >= 24 for all call sites
    stageA(0, 0); stageB(0, 0);
    stageA(1, 32); stageB(1, 32);
    for (int t = 0; t < nt - 1; ++t) {
        asm volatile("s_waitcnt vmcnt(%0)" :: "i"(NL) : "memory");   // tile t landed
        __builtin_amdgcn_sched_barrier(0);
        __builtin_amdgcn_s_barrier();         // all waves: tile t ready, buf (t-1)%3 consumed
        if (t + 2 < nt) {
            int b2 = (t + 2) % 3;
            stageA(b2, (t + 2) * 32);
            stageB(b2, (t + 2) * 32);
        }
        compute(t % 3);
    }
    asm volatile("s_waitcnt vmcnt(0)" ::: "memory");                  // last tile landed
    __builtin_amdgcn_sched_barrier(0);
    __builtin_amdgcn_s_barrier();
    compute((nt - 1) % 3);

    int rr = q4 * 4;
    if (mode == 1) {
        short* base = outB + (size_t)which * ROWS * D;
        #pragma unroll
        for (int m = 0; m < MR; ++m) {
            int rowb = row0 + wr + m * 16 + rr;
            int b2 = rowb >> 9, s0 = rowb & 511;
            #pragma unroll
            for (int n = 0; n < 4; ++n) {
                int col = ncol0 + wc + n * 16 + fr;
                int h2 = col >> 6, d2 = col & 63;
                float bv = Bv[col];
                if (which == 2) {
                    bf16x4 pk;
                    #pragma unroll
                    for (int ri = 0; ri < 4; ++ri) pk[ri] = f2b(acc[m][n][ri] + bv);
                    *(bf16x4*)&base[(((size_t)b2 * H + h2) * 64 + d2) * 512 + s0] = pk;
                } else {
                    #pragma unroll
                    for (int ri = 0; ri < 4; ++ri)
                        base[(((size_t)b2 * H + h2) * 512 + (s0 + ri)) * 64 + d2] =
                            f2b((acc[m][n][ri] + bv) * alpha);
                }
            }
        }
        return;
    }

    #pragma unroll
    for (int m = 0; m < MR; ++m) {
        #pragma unroll
        for (int n = 0; n < 4; ++n) {
            int col  = ncol0 + wc + n * 16 + fr;
            float bv = Bv[col];
            #pragma unroll
            for (int ri = 0; ri < 4; ++ri) {
                int row = row0 + wr + m * 16 + rr + ri;
                size_t idx = (size_t)row * nper + col;
                float val = acc[m][n][ri] + bv;
                if (mode == 2) {
                    outB[idx] = f2b(gelu_f(val));
                } else {
                    outF[idx] = val + resid[idx];
                }
            }
        }
    }
}

// ---------------------------------------------------------------------------
// LDS-staged online-softmax attention (round-10, verified).
// ---------------------------------------------------------------------------
__global__ __launch_bounds__(256) void attn_kernel(
    const short* __restrict__ qb, const short* __restrict__ kbuf,
    const short* __restrict__ vtb,
    const uint32_t* __restrict__ pb,
    const float* __restrict__ vd, const float* __restrict__ ac,
    short* __restrict__ o)
{
    __shared__ __align__(16) short Ks[2][128 * 64];
    __shared__ __align__(16) short Vs[2][64 * 128];
    int tid = threadIdx.x, lane = tid & 63, w = tid >> 6;
    int bid = blockIdx.x;
    int b    = bid & 7;
    int qblk = (bid >> 3) & 7;
    int hh   = bid >> 6;
    int fr = lane & 15, g16 = lane >> 4;
    int kb8 = g16 * 8, rr = g16 * 4;
    int i0 = qblk * 64 + w * 16;
    int i  = i0 + fr;

    const short* qp = qb   + ((size_t)(b * H + hh) * S) * 64;
    const short* kp = kbuf + ((size_t)(b * H + hh) * S) * 64;
    const short* vp = vtb  + ((size_t)(b * H + hh) * 64) * S;

    bf16x8 aq0 = *(const bf16x8*)&qp[(i0 + fr) * 64 + kb8];
    bf16x8 aq1 = *(const bf16x8*)&qp[(i0 + fr) * 64 + 32 + kb8];

    float Ah = ac[hh], Ch = ac[16 + hh], th = vd[hh];
    const uint32_t* pbb = pb + (size_t)b * S * S + (size_t)i * S;

    auto stageK = [&](int buf, int j0) {
        #pragma unroll
        for (int ii = 0; ii < 4; ++ii) {
            int U = ii * 256 + tid;
            int r = U >> 3;
            int ch = (U & 7) ^ (r & 7);
            gload16(kp + (size_t)(j0 + r) * 64 + ch * 8,
                    (char*)&Ks[buf][0] + ((size_t)ii * 256 + w * 64) * 16);
        }
    };
    auto stageV = [&](int buf, int j0) {
        #pragma unroll
        for (int ii = 0; ii < 4; ++ii) {
            int U = ii * 256 + tid;
            int d = U >> 4;
            int s8 = (2 * (U & 15)) ^ (d & 14);
            gload16(vp + (size_t)d * S + j0 + s8 * 4,
                    (char*)&Vs[buf][0] + ((size_t)ii * 256 + w * 64) * 16);
        }
    };

    float m_run = -3.0e38f, l_run = 0.f;
    f32x4 oacc[4] = {};

    stageK(0, 0);
    stageV(0, 0);
    __syncthreads();
    int buf = 0;
    #pragma unroll 1
    for (int t = 0; t < 4; ++t) {
        if (t < 3) { stageK(buf ^ 1, (t + 1) * 128); stageV(buf ^ 1, (t + 1) * 128); }
        f32x4 s[8];
        #pragma unroll
        for (int jt = 0; jt < 8; ++jt) {
            int jb = t * 8 + jt;
            u32x4 u = *(const u32x4*)&pbb[jb * 16 + rr];
            f32x4 c;
            #pragma unroll
            for (int ri = 0; ri < 4; ++ri) {
                int j = jb * 16 + rr + ri;
                float bias = b2f_lo(u[ri]);
                if (i > 0 && j > 0) bias += b2f_hi(u[ri]) * Ah + Ch;
                if (i == 0 || j == 0) bias += th;
                c[ri] = bias;
            }
            int r = jt * 16 + fr;
            const char* krow = (const char*)&Ks[buf][0] + r * 128;
            bf16x8 kf0 = *(const bf16x8*)(krow + ((g16 ^ (r & 7)) * 16));
            bf16x8 kf1 = *(const bf16x8*)(krow + (((g16 + 4) ^ (r & 7)) * 16));
            c = __builtin_amdgcn_mfma_f32_16x16x32_bf16(kf0, aq0, c, 0, 0, 0);
            s[jt] = __builtin_amdgcn_mfma_f32_16x16x32_bf16(kf1, aq1, c, 0, 0, 0);
        }
        float tm = s[0][0];
        #pragma unroll
        for (int jt = 0; jt < 8; ++jt)
            #pragma unroll
            for (int ri = 0; ri < 4; ++ri) tm = fmaxf(tm, s[jt][ri]);
        tm = fmaxf(tm, __shfl_xor(tm, 16));
        tm = fmaxf(tm, __shfl_xor(tm, 32));
        float mnew = fmaxf(m_run, tm);
        float scale = __expf(m_run - mnew);
        l_run *= scale;
        #pragma unroll
        for (int ri = 0; ri < 4; ++ri) {
            float scr = __shfl(scale, rr + ri);
            #pragma unroll
            for (int dt = 0; dt < 4; ++dt) oacc[dt][ri] *= scr;
        }
        #pragma unroll
        for (int jt = 0; jt < 8; ++jt)
            #pragma unroll
            for (int ri = 0; ri < 4; ++ri) {
                float p = __expf(s[jt][ri] - mnew);
                s[jt][ri] = p;
                l_run += p;
            }
        #pragma unroll
        for (int jt = 0; jt < 8; ++jt) {
            bf16x4 pa;
            #pragma unroll
            for (int ri = 0; ri < 4; ++ri) pa[ri] = f2b(s[jt][ri]);
            #pragma unroll
            for (int dt = 0; dt < 4; ++dt) {
                int d = dt * 16 + fr;
                const char* vrow = (const char*)&Vs[buf][0] + d * 256;
                bf16x4 vb = *(const bf16x4*)(vrow + (((jt * 4 + g16) ^ (d & 14)) * 8));
                oacc[dt] = mfma16(pa, vb, oacc[dt]);
            }
        }
        m_run = mnew;
        __syncthreads();
        buf ^= 1;
    }
    mfma16_fence(oacc);

    l_run += __shfl_xor(l_run, 16);
    l_run += __shfl_xor(l_run, 32);
    float invl = 1.f / l_run;
    #pragma unroll
    for (int ri = 0; ri < 4; ++ri) {
        float ivr = __shfl(invl, rr + ri);
        #pragma unroll
        for (int dt = 0; dt < 4; ++dt)
            o[((size_t)(b * S + i0 + rr + ri) * H + hh) * 64 + dt * 16 + fr] =
                f2b(oacc[dt][ri] * ivr);
    }
}

// ---------------------------------------------------------------------------
extern "C" void kernel_launch(void* const* d_in, const int* in_sizes, int n_in,
                              void* d_out, int out_size, void* d_ws, size_t ws_size,
                              hipStream_t stream)
{
    const float* attn_bias   = (const float*)d_in[0];
    const float* spatial_pos = (const float*)d_in[1];
    const int*   xx          = (const int*)d_in[2];
    const float* node_emb    = (const float*)d_in[3];
    const float* graph_token = (const float*)d_in[4];
    const float* virt_dist   = (const float*)d_in[5];
    const float* sp_w1 = (const float*)d_in[6];
    const float* sp_b1 = (const float*)d_in[7];
    const float* sp_w2 = (const float*)d_in[8];
    const float* sp_b2 = (const float*)d_in[9];
    const float* ln1_s = (const float*)d_in[10];
    const float* ln1_b = (const float*)d_in[11];
    const float* wq = (const float*)d_in[12];
    const float* bq = (const float*)d_in[13];
    const float* wk = (const float*)d_in[14];
    const float* bk = (const float*)d_in[15];
    const float* wv = (const float*)d_in[16];
    const float* bv = (const float*)d_in[17];
    const float* wo = (const float*)d_in[18];
    const float* bo = (const float*)d_in[19];
    const float* ln2_s = (const float*)d_in[20];
    const float* ln2_b = (const float*)d_in[21];
    const float* fw1 = (const float*)d_in[22];
    const float* fb1 = (const float*)d_in[23];
    const float* fw2 = (const float*)d_in[24];
    const float* fb2 = (const float*)d_in[25];
    const float* fln_s = (const float*)d_in[26];
    const float* fln_b = (const float*)d_in[27];

    float* wsf = (float*)d_ws;
    const size_t SZ = (size_t)ROWS * D;        // 3,145,728
    float* h   = wsf;                          // f32 [ROWS][D]
    float* acb = wsf + SZ;                     // A[12],C[12]
    short* s16 = (short*)(wsf + SZ + 64);
    short* yob = s16;                          // bf16 [ROWS][D]
    short* g16b = s16 + SZ;                    // bf16 [ROWS][FFN]
    short* bfq = g16b + (size_t)ROWS * FFN;    // 3 x bf16 [ROWS*D]
    short* wqkvT = bfq + 3 * SZ;               // [2304][768]
    short* woT   = wqkvT + 2304 * 768;         // [768][768]
    short* f1T   = woT + 768 * 768;            // [3072][768]
    short* f2T   = f1T + (size_t)3072 * 768;   // [768][3072]
    uint32_t* pbias = (uint32_t*)(f2T + (size_t)768 * 3072);  // [B][S][S] u32

    embed_kernel<<<ROWS, 256, 0, stream>>>(xx, node_emb, graph_token, h);
    ac_kernel<<<1, 64, 0, stream>>>(sp_w1, sp_b1, sp_w2, sp_b2, acb);
    bias_pack_kernel<<<ROWS, 256, 0, stream>>>(attn_bias, spatial_pos, pbias);

    for (int l = 0; l < 6; ++l) {
        wcvt_kernel<<<1728, 256, 0, stream>>>(
            wq + (size_t)l * D * D, wk + (size_t)l * D * D, wv + (size_t)l * D * D,
            wo + (size_t)l * D * D, fw1 + (size_t)l * D * FFN, fw2 + (size_t)l * FFN * D,
            wqkvT, woT, f1T, f2T);
        ln_kernel<<<ROWS, 256, 0, stream>>>(h, ln1_s + l * D, ln1_b + l * D, nullptr, yob);
        gemm2<128><<<576, 256, 0, stream>>>(
            yob, wqkvT, bq + l * D, bk + l * D, bv + l * D,
            nullptr, nullptr, bfq, D, D, 32, 0.125f, 1);
        attn_kernel<<<B * H * 8, 256, 0, stream>>>(
            bfq, bfq + SZ, bfq + 2 * SZ, pbias, virt_dist, acb, yob);
        gemm2<64><<<384, 256, 0, stream>>>(
            yob, woT, bo + l * D, nullptr, nullptr,
            h, h, nullptr, D, D, 64, 1.0f, 0);
        ln_kernel<<<ROWS, 256, 0, stream>>>(h, ln2_s + l * D, ln2_b + l * D, nullptr, yob);
        gemm2<128><<<768, 256, 0, stream>>>(
            yob, f1T, fb1 + l * FFN, nullptr, nullptr,
            nullptr, nullptr, g16b, D, FFN, 32, 1.0f, 2);
        gemm2<64><<<384, 256, 0, stream>>>(
            g16b, f2T, fb2 + l * D, nullptr, nullptr,
            h, h, nullptr, FFN, D, 64, 1.0f, 0);
    }
    ln_kernel<<<ROWS, 256, 0, stream>>>(h, fln_s, fln_b, (float*)d_out, nullptr);
}

// Round 16
// 1135.373 us; speedup vs baseline: 1.2586x; 1.0811x over previous
//
#include <hip/hip_runtime.h>
#include <cstdint>
#include <cstddef>

// ---------------------------------------------------------------------------
// Graphormer-ish encoder forward, MI355X (gfx950).
// Round 15: template<BM,BN> GEMM; o-proj and FFN2 (N=768) move from
// 64x128-tile/384-block (1.5 blk/CU, TLP-starved) to 64x64-tile/768-block
// (3 blk/CU, 24KB LDS -> 6 blk/CU capacity). QKV/FFN1 unchanged <128,128>.
// Depth-2 counted-vmcnt pipeline kept from round 14.
// ---------------------------------------------------------------------------

typedef __attribute__((ext_vector_type(8))) short bf16x8;
typedef __attribute__((ext_vector_type(4))) short bf16x4;
typedef __attribute__((ext_vector_type(4))) float f32x4;
typedef __attribute__((ext_vector_type(4))) unsigned int u32x4;

static constexpr int D    = 768;
static constexpr int H    = 12;
static constexpr int S    = 512;
static constexpr int NN   = 511;
static constexpr int B    = 8;
static constexpr int FFN  = 3072;
static constexpr int ROWS = B * S;   // 4096

__device__ __forceinline__ short f2b(float x) {
    union { float f; uint32_t u; } c; c.f = x;
    uint32_t r = (c.u + 0x7fffu + ((c.u >> 16) & 1u)) >> 16;  // RNE
    return (short)(uint16_t)r;
}
__device__ __forceinline__ float b2f_lo(uint32_t u) {
    union { uint32_t u; float f; } c; c.u = u << 16; return c.f;
}
__device__ __forceinline__ float b2f_hi(uint32_t u) {
    union { uint32_t u; float f; } c; c.u = u & 0xffff0000u; return c.f;
}
__device__ __forceinline__ float gelu_f(float x) {
    return 0.5f * x * (1.0f + erff(x * 0.7071067811865476f));
}
__device__ __forceinline__ void gload16(const void* g, void* l) {
    __builtin_amdgcn_global_load_lds(
        (const __attribute__((address_space(1))) void*)g,
        (__attribute__((address_space(3))) void*)l, 16, 0, 0);
}

// PV MFMA: 16x16x16 bf16 (builtin -> compiler handles MFMA hazards).
#if __has_builtin(__builtin_amdgcn_mfma_f32_16x16x16bf16_1k)
__device__ __forceinline__ f32x4 mfma16(bf16x4 a, bf16x4 b, f32x4 c) {
    return __builtin_amdgcn_mfma_f32_16x16x16bf16_1k(a, b, c, 0, 0, 0);
}
__device__ __forceinline__ void mfma16_fence(f32x4* o) { (void)o; }
#else
__device__ __forceinline__ f32x4 mfma16(bf16x4 a, bf16x4 b, f32x4 c) {
    asm volatile("s_nop 1\n\tv_mfma_f32_16x16x16_bf16 %0, %1, %2, %0"
                 : "+v"(c) : "v"(a), "v"(b));
    return c;
}
__device__ __forceinline__ void mfma16_fence(f32x4* o) {
    asm volatile("s_nop 7\n\ts_nop 7"
                 : "+v"(o[0]), "+v"(o[1]), "+v"(o[2]), "+v"(o[3]));
}
#endif

// ---------------------------------------------------------------------------
__global__ __launch_bounds__(256) void embed_kernel(
    const int* __restrict__ x, const float* __restrict__ emb,
    const float* __restrict__ gtok, float* __restrict__ h)
{
    int row = blockIdx.x;
    int b = row >> 9, s = row & (S - 1);
    const float* src = (s == 0) ? gtok : (emb + (size_t)x[b * NN + (s - 1)] * D);
    float* dst = h + (size_t)row * D;
    int t = threadIdx.x;
    dst[t]       = src[t];
    dst[t + 256] = src[t + 256];
    dst[t + 512] = src[t + 512];
}

// ---------------------------------------------------------------------------
__global__ void ac_kernel(const float* __restrict__ w1, const float* __restrict__ b1,
                          const float* __restrict__ w2, const float* __restrict__ b2,
                          float* __restrict__ ac)
{
    int h = threadIdx.x;
    if (h < H) {
        float a = 0.f, c = 0.f;
        for (int k = 0; k < 128; ++k) { a += w1[k] * w2[k * H + h]; c += b1[k] * w2[k * H + h]; }
        ac[h] = a; ac[16 + h] = c + b2[h];
    }
}

// ---------------------------------------------------------------------------
// Bias pack, [b][i][j] layout: pb[b,i,j] = u32( bf16(2*ab) | bf16(sp)<<16 )
// ---------------------------------------------------------------------------
__global__ __launch_bounds__(256) void bias_pack_kernel(
    const float* __restrict__ ab, const float* __restrict__ sp,
    uint32_t* __restrict__ pb)
{
    int row = blockIdx.x;                 // b*S + i
    int b = row >> 9, i = row & 511;
    const float* abr = ab + (size_t)row * S;
    const float* spr = sp + ((size_t)b * NN + (i - 1)) * NN;
    uint32_t* out = pb + (size_t)row * S;
    #pragma unroll
    for (int jt = 0; jt < 2; ++jt) {
        int j = jt * 256 + threadIdx.x;
        float a2 = 2.f * abr[j];
        float spv = (i > 0 && j > 0) ? spr[j - 1] : 0.f;
        out[j] = (uint32_t)(uint16_t)f2b(a2) | ((uint32_t)(uint16_t)f2b(spv) << 16);
    }
}

// ---------------------------------------------------------------------------
// Per-layer weight convert+transpose: f32 [R][C] -> bf16 [C][R].
// ---------------------------------------------------------------------------
__global__ __launch_bounds__(256) void wcvt_kernel(
    const float* __restrict__ wq, const float* __restrict__ wk,
    const float* __restrict__ wv, const float* __restrict__ wo,
    const float* __restrict__ f1, const float* __restrict__ f2,
    short* __restrict__ wqkvT, short* __restrict__ woT,
    short* __restrict__ f1T, short* __restrict__ f2T)
{
    int t = blockIdx.x;
    const float* in; short* out; int R, C, tr, tc;
    if (t < 432) {
        int which = t / 144, tt = t - which * 144;
        in = (which == 0) ? wq : ((which == 1) ? wk : wv);
        out = wqkvT + (size_t)which * 768 * 768;
        R = 768; C = 768; tr = tt / 12; tc = tt % 12;
    } else if (t < 576) {
        int tt = t - 432; in = wo; out = woT; R = 768; C = 768; tr = tt / 12; tc = tt % 12;
    } else if (t < 1152) {
        int tt = t - 576; in = f1; out = f1T; R = 768; C = 3072; tr = tt / 48; tc = tt % 48;
    } else {
        int tt = t - 1152; in = f2; out = f2T; R = 3072; C = 768; tr = tt / 12; tc = tt % 12;
    }
    int r0 = tr * 64, c0 = tc * 64;
    __shared__ short tile[64][65];
    int tid = threadIdx.x;
    #pragma unroll
    for (int i = 0; i < 16; ++i) {
        int e = i * 256 + tid; int r = e >> 6, c = e & 63;
        tile[r][c] = f2b(in[(size_t)(r0 + r) * C + c0 + c]);
    }
    __syncthreads();
    #pragma unroll
    for (int i = 0; i < 16; ++i) {
        int e = i * 256 + tid; int c = e >> 6, r = e & 63;
        out[(size_t)(c0 + c) * R + r0 + r] = tile[r][c];
    }
}

// ---------------------------------------------------------------------------
__global__ __launch_bounds__(256) void ln_kernel(
    const float* __restrict__ in, const float* __restrict__ sc,
    const float* __restrict__ bi, float* __restrict__ outF,
    short* __restrict__ outB)
{
    int row = blockIdx.x, t = threadIdx.x;
    const float* x = in + (size_t)row * D;
    float e0 = x[t], e1 = x[t + 256], e2 = x[t + 512];
    float s  = e0 + e1 + e2;
    float sq = e0 * e0 + e1 * e1 + e2 * e2;
    #pragma unroll
    for (int off = 1; off < 64; off <<= 1) { s += __shfl_xor(s, off); sq += __shfl_xor(sq, off); }
    __shared__ float red[8];
    int w = t >> 6, lane = t & 63;
    if (lane == 0) { red[w] = s; red[4 + w] = sq; }
    __syncthreads();
    s  = red[0] + red[1] + red[2] + red[3];
    sq = red[4] + red[5] + red[6] + red[7];
    float m   = s * (1.f / D);
    float inv = rsqrtf(sq * (1.f / D) - m * m + 1e-5f);
    float v0 = (e0 - m) * inv * sc[t]       + bi[t];
    float v1 = (e1 - m) * inv * sc[t + 256] + bi[t + 256];
    float v2 = (e2 - m) * inv * sc[t + 512] + bi[t + 512];
    if (outB) {
        short* o = outB + (size_t)row * D;
        o[t] = f2b(v0); o[t + 256] = f2b(v1); o[t + 512] = f2b(v2);
    } else {
        float* o = outF + (size_t)row * D;
        o[t] = v0; o[t + 256] = v1; o[t + 512] = v2;
    }
}

// ---------------------------------------------------------------------------
// bf16 MFMA GEMM, BM x BN tile, BK=32, swizzle chunk ^= (r>>1)&3 both-sides.
// Depth-2 pipeline: 3 LDS buffers, counted vmcnt + raw s_barrier.
// 4 waves in 2x2; wave tile (BM/2)x(BN/2); MR=BM/32, NR=BN/32 frags.
// ---------------------------------------------------------------------------
template<int BM, int BN>
__global__ __launch_bounds__(256) void gemm2(
    const short* __restrict__ A, const short* __restrict__ Wt,
    const float* __restrict__ Bb0, const float* __restrict__ Bb1, const float* __restrict__ Bb2,
    float* __restrict__ outF, const float* __restrict__ resid,
    short* __restrict__ outB,
    int K, int nper, int gx, float alpha0, int mode)
{
    constexpr int MR = BM / 32;
    constexpr int NR = BN / 32;
    constexpr int NL = BM / 64 + BN / 64;    // per-thread global_load_lds per tile
    __shared__ __align__(16) short As[3][BM * 32];
    __shared__ __align__(16) short Bs[3][BN * 32];
    int tid  = threadIdx.x;
    int lane = tid & 63;
    int w    = tid >> 6;

    int nwg = gridDim.x;
    int bid = blockIdx.x;
    int sid = (bid & 7) * (nwg >> 3) + (bid >> 3);
    int row0 = (sid % gx) * BM;
    int n0   = (sid / gx) * BN;

    int which = n0 / nper;
    int ncol0 = n0 - which * nper;
    const float* Bv = (which == 0) ? Bb0 : ((which == 1) ? Bb1 : Bb2);
    float alpha = (which == 0) ? alpha0 : 1.0f;

    int wr = (w >> 1) * (BM / 2);
    int wc = (w & 1) * (BN / 2);
    int fr = lane & 15;
    int q4 = lane >> 4;          // 0..3 (16B chunk within 64B row)

    f32x4 acc[MR][NR] = {};

    auto stageA = [&](int buf, int k0) {
        #pragma unroll
        for (int ii = 0; ii < BM / 64; ++ii) {
            int U = ii * 256 + tid;          // 16B unit
            int r = U >> 2;
            int ch = (U & 3) ^ ((r >> 1) & 3);
            gload16(A + (size_t)(row0 + r) * K + k0 + ch * 8,
                    (char*)&As[buf][0] + ((size_t)ii * 256 + w * 64) * 16);
        }
    };
    auto stageB = [&](int buf, int k0) {
        #pragma unroll
        for (int ii = 0; ii < BN / 64; ++ii) {
            int U = ii * 256 + tid;
            int r = U >> 2;
            int ch = (U & 3) ^ ((r >> 1) & 3);
            gload16(Wt + (size_t)(n0 + r) * K + k0 + ch * 8,
                    (char*)&Bs[buf][0] + ((size_t)ii * 256 + w * 64) * 16);
        }
    };
    auto compute = [&](int buf) {
        bf16x8 af[MR], bfr[NR];
        #pragma unroll
        for (int m = 0; m < MR; ++m) {
            int r = wr + m * 16 + fr;
            af[m] = *(const bf16x8*)((const char*)&As[buf][0]
                    + (size_t)r * 64 + ((q4 ^ ((r >> 1) & 3)) * 16));
        }
        #pragma unroll
        for (int n = 0; n < NR; ++n) {
            int r = wc + n * 16 + fr;
            bfr[n] = *(const bf16x8*)((const char*)&Bs[buf][0]
                    + (size_t)r * 64 + ((q4 ^ ((r >> 1) & 3)) * 16));
        }
        #pragma unroll
        for (int m = 0; m < MR; ++m)
            #pragma unroll
            for (int n = 0; n < NR; ++n)
                acc[m][n] = __builtin_amdgcn_mfma_f32_16x16x32_bf16(af[m], bfr[n], acc[m][n], 0, 0, 0);
    };

    int nt = K >> 5;
    stageA(0, 0); stageB(0, 0);
    stageA(1, 32); stageB(1, 32);
    for (int t = 0; t < nt - 1; ++t) {
        asm volatile("s_waitcnt vmcnt(%0)" :: "i"(NL) : "memory");   // tile t landed
        __builtin_amdgcn_sched_barrier(0);
        __builtin_amdgcn_s_barrier();
        if (t + 2 < nt) {
            int b2 = (t + 2) % 3;
            stageA(b2, (t + 2) * 32);
            stageB(b2, (t + 2) * 32);
        }
        compute(t % 3);
    }
    asm volatile("s_waitcnt vmcnt(0)" ::: "memory");
    __builtin_amdgcn_sched_barrier(0);
    __builtin_amdgcn_s_barrier();
    compute((nt - 1) % 3);

    int rr = q4 * 4;
    if (mode == 1) {
        short* base = outB + (size_t)which * ROWS * D;
        #pragma unroll
        for (int m = 0; m < MR; ++m) {
            int rowb = row0 + wr + m * 16 + rr;
            int b2 = rowb >> 9, s0 = rowb & 511;
            #pragma unroll
            for (int n = 0; n < NR; ++n) {
                int col = ncol0 + wc + n * 16 + fr;
                int h2 = col >> 6, d2 = col & 63;
                float bv = Bv[col];
                if (which == 2) {
                    bf16x4 pk;
                    #pragma unroll
                    for (int ri = 0; ri < 4; ++ri) pk[ri] = f2b(acc[m][n][ri] + bv);
                    *(bf16x4*)&base[(((size_t)b2 * H + h2) * 64 + d2) * 512 + s0] = pk;
                } else {
                    #pragma unroll
                    for (int ri = 0; ri < 4; ++ri)
                        base[(((size_t)b2 * H + h2) * 512 + (s0 + ri)) * 64 + d2] =
                            f2b((acc[m][n][ri] + bv) * alpha);
                }
            }
        }
        return;
    }

    #pragma unroll
    for (int m = 0; m < MR; ++m) {
        #pragma unroll
        for (int n = 0; n < NR; ++n) {
            int col  = ncol0 + wc + n * 16 + fr;
            float bv = Bv[col];
            #pragma unroll
            for (int ri = 0; ri < 4; ++ri) {
                int row = row0 + wr + m * 16 + rr + ri;
                size_t idx = (size_t)row * nper + col;
                float val = acc[m][n][ri] + bv;
                if (mode == 2) {
                    outB[idx] = f2b(gelu_f(val));
                } else {
                    outF[idx] = val + resid[idx];
                }
            }
        }
    }
}

// ---------------------------------------------------------------------------
// LDS-staged online-softmax attention (round-10, verified).
// ---------------------------------------------------------------------------
__global__ __launch_bounds__(256) void attn_kernel(
    const short* __restrict__ qb, const short* __restrict__ kbuf,
    const short* __restrict__ vtb,
    const uint32_t* __restrict__ pb,
    const float* __restrict__ vd, const float* __restrict__ ac,
    short* __restrict__ o)
{
    __shared__ __align__(16) short Ks[2][128 * 64];
    __shared__ __align__(16) short Vs[2][64 * 128];
    int tid = threadIdx.x, lane = tid & 63, w = tid >> 6;
    int bid = blockIdx.x;
    int b    = bid & 7;
    int qblk = (bid >> 3) & 7;
    int hh   = bid >> 6;
    int fr = lane & 15, g16 = lane >> 4;
    int kb8 = g16 * 8, rr = g16 * 4;
    int i0 = qblk * 64 + w * 16;
    int i  = i0 + fr;

    const short* qp = qb   + ((size_t)(b * H + hh) * S) * 64;
    const short* kp = kbuf + ((size_t)(b * H + hh) * S) * 64;
    const short* vp = vtb  + ((size_t)(b * H + hh) * 64) * S;

    bf16x8 aq0 = *(const bf16x8*)&qp[(i0 + fr) * 64 + kb8];
    bf16x8 aq1 = *(const bf16x8*)&qp[(i0 + fr) * 64 + 32 + kb8];

    float Ah = ac[hh], Ch = ac[16 + hh], th = vd[hh];
    const uint32_t* pbb = pb + (size_t)b * S * S + (size_t)i * S;

    auto stageK = [&](int buf, int j0) {
        #pragma unroll
        for (int ii = 0; ii < 4; ++ii) {
            int U = ii * 256 + tid;
            int r = U >> 3;
            int ch = (U & 7) ^ (r & 7);
            gload16(kp + (size_t)(j0 + r) * 64 + ch * 8,
                    (char*)&Ks[buf][0] + ((size_t)ii * 256 + w * 64) * 16);
        }
    };
    auto stageV = [&](int buf, int j0) {
        #pragma unroll
        for (int ii = 0; ii < 4; ++ii) {
            int U = ii * 256 + tid;
            int d = U >> 4;
            int s8 = (2 * (U & 15)) ^ (d & 14);
            gload16(vp + (size_t)d * S + j0 + s8 * 4,
                    (char*)&Vs[buf][0] + ((size_t)ii * 256 + w * 64) * 16);
        }
    };

    float m_run = -3.0e38f, l_run = 0.f;
    f32x4 oacc[4] = {};

    stageK(0, 0);
    stageV(0, 0);
    __syncthreads();
    int buf = 0;
    #pragma unroll 1
    for (int t = 0; t < 4; ++t) {
        if (t < 3) { stageK(buf ^ 1, (t + 1) * 128); stageV(buf ^ 1, (t + 1) * 128); }
        f32x4 s[8];
        #pragma unroll
        for (int jt = 0; jt < 8; ++jt) {
            int jb = t * 8 + jt;
            u32x4 u = *(const u32x4*)&pbb[jb * 16 + rr];
            f32x4 c;
            #pragma unroll
            for (int ri = 0; ri < 4; ++ri) {
                int j = jb * 16 + rr + ri;
                float bias = b2f_lo(u[ri]);
                if (i > 0 && j > 0) bias += b2f_hi(u[ri]) * Ah + Ch;
                if (i == 0 || j == 0) bias += th;
                c[ri] = bias;
            }
            int r = jt * 16 + fr;
            const char* krow = (const char*)&Ks[buf][0] + r * 128;
            bf16x8 kf0 = *(const bf16x8*)(krow + ((g16 ^ (r & 7)) * 16));
            bf16x8 kf1 = *(const bf16x8*)(krow + (((g16 + 4) ^ (r & 7)) * 16));
            c = __builtin_amdgcn_mfma_f32_16x16x32_bf16(kf0, aq0, c, 0, 0, 0);
            s[jt] = __builtin_amdgcn_mfma_f32_16x16x32_bf16(kf1, aq1, c, 0, 0, 0);
        }
        float tm = s[0][0];
        #pragma unroll
        for (int jt = 0; jt < 8; ++jt)
            #pragma unroll
            for (int ri = 0; ri < 4; ++ri) tm = fmaxf(tm, s[jt][ri]);
        tm = fmaxf(tm, __shfl_xor(tm, 16));
        tm = fmaxf(tm, __shfl_xor(tm, 32));
        float mnew = fmaxf(m_run, tm);
        float scale = __expf(m_run - mnew);
        l_run *= scale;
        #pragma unroll
        for (int ri = 0; ri < 4; ++ri) {
            float scr = __shfl(scale, rr + ri);
            #pragma unroll
            for (int dt = 0; dt < 4; ++dt) oacc[dt][ri] *= scr;
        }
        #pragma unroll
        for (int jt = 0; jt < 8; ++jt)
            #pragma unroll
            for (int ri = 0; ri < 4; ++ri) {
                float p = __expf(s[jt][ri] - mnew);
                s[jt][ri] = p;
                l_run += p;
            }
        #pragma unroll
        for (int jt = 0; jt < 8; ++jt) {
            bf16x4 pa;
            #pragma unroll
            for (int ri = 0; ri < 4; ++ri) pa[ri] = f2b(s[jt][ri]);
            #pragma unroll
            for (int dt = 0; dt < 4; ++dt) {
                int d = dt * 16 + fr;
                const char* vrow = (const char*)&Vs[buf][0] + d * 256;
                bf16x4 vb = *(const bf16x4*)(vrow + (((jt * 4 + g16) ^ (d & 14)) * 8));
                oacc[dt] = mfma16(pa, vb, oacc[dt]);
            }
        }
        m_run = mnew;
        __syncthreads();
        buf ^= 1;
    }
    mfma16_fence(oacc);

    l_run += __shfl_xor(l_run, 16);
    l_run += __shfl_xor(l_run, 32);
    float invl = 1.f / l_run;
    #pragma unroll
    for (int ri = 0; ri < 4; ++ri) {
        float ivr = __shfl(invl, rr + ri);
        #pragma unroll
        for (int dt = 0; dt < 4; ++dt)
            o[((size_t)(b * S + i0 + rr + ri) * H + hh) * 64 + dt * 16 + fr] =
                f2b(oacc[dt][ri] * ivr);
    }
}

// ---------------------------------------------------------------------------
extern "C" void kernel_launch(void* const* d_in, const int* in_sizes, int n_in,
                              void* d_out, int out_size, void* d_ws, size_t ws_size,
                              hipStream_t stream)
{
    const float* attn_bias   = (const float*)d_in[0];
    const float* spatial_pos = (const float*)d_in[1];
    const int*   xx          = (const int*)d_in[2];
    const float* node_emb    = (const float*)d_in[3];
    const float* graph_token = (const float*)d_in[4];
    const float* virt_dist   = (const float*)d_in[5];
    const float* sp_w1 = (const float*)d_in[6];
    const float* sp_b1 = (const float*)d_in[7];
    const float* sp_w2 = (const float*)d_in[8];
    const float* sp_b2 = (const float*)d_in[9];
    const float* ln1_s = (const float*)d_in[10];
    const float* ln1_b = (const float*)d_in[11];
    const float* wq = (const float*)d_in[12];
    const float* bq = (const float*)d_in[13];
    const float* wk = (const float*)d_in[14];
    const float* bk = (const float*)d_in[15];
    const float* wv = (const float*)d_in[16];
    const float* bv = (const float*)d_in[17];
    const float* wo = (const float*)d_in[18];
    const float* bo = (const float*)d_in[19];
    const float* ln2_s = (const float*)d_in[20];
    const float* ln2_b = (const float*)d_in[21];
    const float* fw1 = (const float*)d_in[22];
    const float* fb1 = (const float*)d_in[23];
    const float* fw2 = (const float*)d_in[24];
    const float* fb2 = (const float*)d_in[25];
    const float* fln_s = (const float*)d_in[26];
    const float* fln_b = (const float*)d_in[27];

    float* wsf = (float*)d_ws;
    const size_t SZ = (size_t)ROWS * D;        // 3,145,728
    float* h   = wsf;                          // f32 [ROWS][D]
    float* acb = wsf + SZ;                     // A[12],C[12]
    short* s16 = (short*)(wsf + SZ + 64);
    short* yob = s16;                          // bf16 [ROWS][D]
    short* g16b = s16 + SZ;                    // bf16 [ROWS][FFN]
    short* bfq = g16b + (size_t)ROWS * FFN;    // 3 x bf16 [ROWS*D]
    short* wqkvT = bfq + 3 * SZ;               // [2304][768]
    short* woT   = wqkvT + 2304 * 768;         // [768][768]
    short* f1T   = woT + 768 * 768;            // [3072][768]
    short* f2T   = f1T + (size_t)3072 * 768;   // [768][3072]
    uint32_t* pbias = (uint32_t*)(f2T + (size_t)768 * 3072);  // [B][S][S] u32

    embed_kernel<<<ROWS, 256, 0, stream>>>(xx, node_emb, graph_token, h);
    ac_kernel<<<1, 64, 0, stream>>>(sp_w1, sp_b1, sp_w2, sp_b2, acb);
    bias_pack_kernel<<<ROWS, 256, 0, stream>>>(attn_bias, spatial_pos, pbias);

    for (int l = 0; l < 6; ++l) {
        wcvt_kernel<<<1728, 256, 0, stream>>>(
            wq + (size_t)l * D * D, wk + (size_t)l * D * D, wv + (size_t)l * D * D,
            wo + (size_t)l * D * D, fw1 + (size_t)l * D * FFN, fw2 + (size_t)l * FFN * D,
            wqkvT, woT, f1T, f2T);
        ln_kernel<<<ROWS, 256, 0, stream>>>(h, ln1_s + l * D, ln1_b + l * D, nullptr, yob);
        gemm2<128, 128><<<576, 256, 0, stream>>>(
            yob, wqkvT, bq + l * D, bk + l * D, bv + l * D,
            nullptr, nullptr, bfq, D, D, 32, 0.125f, 1);
        attn_kernel<<<B * H * 8, 256, 0, stream>>>(
            bfq, bfq + SZ, bfq + 2 * SZ, pbias, virt_dist, acb, yob);
        // o-proj: 64x64 tiles -> 64 x 12 = 768 blocks
        gemm2<64, 64><<<768, 256, 0, stream>>>(
            yob, woT, bo + l * D, nullptr, nullptr,
            h, h, nullptr, D, D, 64, 1.0f, 0);
        ln_kernel<<<ROWS, 256, 0, stream>>>(h, ln2_s + l * D, ln2_b + l * D, nullptr, yob);
        gemm2<128, 128><<<768, 256, 0, stream>>>(
            yob, f1T, fb1 + l * FFN, nullptr, nullptr,
            nullptr, nullptr, g16b, D, FFN, 32, 1.0f, 2);
        // FFN2: 64x64 tiles -> 64 x 12 = 768 blocks
        gemm2<64, 64><<<768, 256, 0, stream>>>(
            g16b, f2T, fb2 + l * D, nullptr, nullptr,
            h, h, nullptr, FFN, D, 64, 1.0f, 0);
    }
    ln_kernel<<<ROWS, 256, 0, stream>>>(h, fln_s, fln_b, (float*)d_out, nullptr);
}

// Round 17
// 1120.824 us; speedup vs baseline: 1.2749x; 1.0130x over previous
//
#include <hip/hip_runtime.h>
#include <cstdint>
#include <cstddef>

// ---------------------------------------------------------------------------
// Graphormer-ish encoder forward, MI355X (gfx950).
// Round 16: NFAST tile decode (N-fastest within the XCD chunk) for the
// N=768 GEMMs (FFN2, o-proj) so each XCD's concurrent blocks reuse the same
// A row-tiles from L2 (was: 4x A re-fetch, FETCH 107MB vs 43MB unique).
// QKV/FFN1 keep M-fastest (W-panel locality). Rest unchanged from round 15.
// ---------------------------------------------------------------------------

typedef __attribute__((ext_vector_type(8))) short bf16x8;
typedef __attribute__((ext_vector_type(4))) short bf16x4;
typedef __attribute__((ext_vector_type(4))) float f32x4;
typedef __attribute__((ext_vector_type(4))) unsigned int u32x4;

static constexpr int D    = 768;
static constexpr int H    = 12;
static constexpr int S    = 512;
static constexpr int NN   = 511;
static constexpr int B    = 8;
static constexpr int FFN  = 3072;
static constexpr int ROWS = B * S;   // 4096

__device__ __forceinline__ short f2b(float x) {
    union { float f; uint32_t u; } c; c.f = x;
    uint32_t r = (c.u + 0x7fffu + ((c.u >> 16) & 1u)) >> 16;  // RNE
    return (short)(uint16_t)r;
}
__device__ __forceinline__ float b2f_lo(uint32_t u) {
    union { uint32_t u; float f; } c; c.u = u << 16; return c.f;
}
__device__ __forceinline__ float b2f_hi(uint32_t u) {
    union { uint32_t u; float f; } c; c.u = u & 0xffff0000u; return c.f;
}
__device__ __forceinline__ float gelu_f(float x) {
    return 0.5f * x * (1.0f + erff(x * 0.7071067811865476f));
}
__device__ __forceinline__ void gload16(const void* g, void* l) {
    __builtin_amdgcn_global_load_lds(
        (const __attribute__((address_space(1))) void*)g,
        (__attribute__((address_space(3))) void*)l, 16, 0, 0);
}

// PV MFMA: 16x16x16 bf16 (builtin -> compiler handles MFMA hazards).
#if __has_builtin(__builtin_amdgcn_mfma_f32_16x16x16bf16_1k)
__device__ __forceinline__ f32x4 mfma16(bf16x4 a, bf16x4 b, f32x4 c) {
    return __builtin_amdgcn_mfma_f32_16x16x16bf16_1k(a, b, c, 0, 0, 0);
}
__device__ __forceinline__ void mfma16_fence(f32x4* o) { (void)o; }
#else
__device__ __forceinline__ f32x4 mfma16(bf16x4 a, bf16x4 b, f32x4 c) {
    asm volatile("s_nop 1\n\tv_mfma_f32_16x16x16_bf16 %0, %1, %2, %0"
                 : "+v"(c) : "v"(a), "v"(b));
    return c;
}
__device__ __forceinline__ void mfma16_fence(f32x4* o) {
    asm volatile("s_nop 7\n\ts_nop 7"
                 : "+v"(o[0]), "+v"(o[1]), "+v"(o[2]), "+v"(o[3]));
}
#endif

// ---------------------------------------------------------------------------
__global__ __launch_bounds__(256) void embed_kernel(
    const int* __restrict__ x, const float* __restrict__ emb,
    const float* __restrict__ gtok, float* __restrict__ h)
{
    int row = blockIdx.x;
    int b = row >> 9, s = row & (S - 1);
    const float* src = (s == 0) ? gtok : (emb + (size_t)x[b * NN + (s - 1)] * D);
    float* dst = h + (size_t)row * D;
    int t = threadIdx.x;
    dst[t]       = src[t];
    dst[t + 256] = src[t + 256];
    dst[t + 512] = src[t + 512];
}

// ---------------------------------------------------------------------------
__global__ void ac_kernel(const float* __restrict__ w1, const float* __restrict__ b1,
                          const float* __restrict__ w2, const float* __restrict__ b2,
                          float* __restrict__ ac)
{
    int h = threadIdx.x;
    if (h < H) {
        float a = 0.f, c = 0.f;
        for (int k = 0; k < 128; ++k) { a += w1[k] * w2[k * H + h]; c += b1[k] * w2[k * H + h]; }
        ac[h] = a; ac[16 + h] = c + b2[h];
    }
}

// ---------------------------------------------------------------------------
// Bias pack, [b][i][j] layout: pb[b,i,j] = u32( bf16(2*ab) | bf16(sp)<<16 )
// ---------------------------------------------------------------------------
__global__ __launch_bounds__(256) void bias_pack_kernel(
    const float* __restrict__ ab, const float* __restrict__ sp,
    uint32_t* __restrict__ pb)
{
    int row = blockIdx.x;                 // b*S + i
    int b = row >> 9, i = row & 511;
    const float* abr = ab + (size_t)row * S;
    const float* spr = sp + ((size_t)b * NN + (i - 1)) * NN;
    uint32_t* out = pb + (size_t)row * S;
    #pragma unroll
    for (int jt = 0; jt < 2; ++jt) {
        int j = jt * 256 + threadIdx.x;
        float a2 = 2.f * abr[j];
        float spv = (i > 0 && j > 0) ? spr[j - 1] : 0.f;
        out[j] = (uint32_t)(uint16_t)f2b(a2) | ((uint32_t)(uint16_t)f2b(spv) << 16);
    }
}

// ---------------------------------------------------------------------------
// Per-layer weight convert+transpose: f32 [R][C] -> bf16 [C][R].
// ---------------------------------------------------------------------------
__global__ __launch_bounds__(256) void wcvt_kernel(
    const float* __restrict__ wq, const float* __restrict__ wk,
    const float* __restrict__ wv, const float* __restrict__ wo,
    const float* __restrict__ f1, const float* __restrict__ f2,
    short* __restrict__ wqkvT, short* __restrict__ woT,
    short* __restrict__ f1T, short* __restrict__ f2T)
{
    int t = blockIdx.x;
    const float* in; short* out; int R, C, tr, tc;
    if (t < 432) {
        int which = t / 144, tt = t - which * 144;
        in = (which == 0) ? wq : ((which == 1) ? wk : wv);
        out = wqkvT + (size_t)which * 768 * 768;
        R = 768; C = 768; tr = tt / 12; tc = tt % 12;
    } else if (t < 576) {
        int tt = t - 432; in = wo; out = woT; R = 768; C = 768; tr = tt / 12; tc = tt % 12;
    } else if (t < 1152) {
        int tt = t - 576; in = f1; out = f1T; R = 768; C = 3072; tr = tt / 48; tc = tt % 48;
    } else {
        int tt = t - 1152; in = f2; out = f2T; R = 3072; C = 768; tr = tt / 12; tc = tt % 12;
    }
    int r0 = tr * 64, c0 = tc * 64;
    __shared__ short tile[64][65];
    int tid = threadIdx.x;
    #pragma unroll
    for (int i = 0; i < 16; ++i) {
        int e = i * 256 + tid; int r = e >> 6, c = e & 63;
        tile[r][c] = f2b(in[(size_t)(r0 + r) * C + c0 + c]);
    }
    __syncthreads();
    #pragma unroll
    for (int i = 0; i < 16; ++i) {
        int e = i * 256 + tid; int c = e >> 6, r = e & 63;
        out[(size_t)(c0 + c) * R + r0 + r] = tile[r][c];
    }
}

// ---------------------------------------------------------------------------
__global__ __launch_bounds__(256) void ln_kernel(
    const float* __restrict__ in, const float* __restrict__ sc,
    const float* __restrict__ bi, float* __restrict__ outF,
    short* __restrict__ outB)
{
    int row = blockIdx.x, t = threadIdx.x;
    const float* x = in + (size_t)row * D;
    float e0 = x[t], e1 = x[t + 256], e2 = x[t + 512];
    float s  = e0 + e1 + e2;
    float sq = e0 * e0 + e1 * e1 + e2 * e2;
    #pragma unroll
    for (int off = 1; off < 64; off <<= 1) { s += __shfl_xor(s, off); sq += __shfl_xor(sq, off); }
    __shared__ float red[8];
    int w = t >> 6, lane = t & 63;
    if (lane == 0) { red[w] = s; red[4 + w] = sq; }
    __syncthreads();
    s  = red[0] + red[1] + red[2] + red[3];
    sq = red[4] + red[5] + red[6] + red[7];
    float m   = s * (1.f / D);
    float inv = rsqrtf(sq * (1.f / D) - m * m + 1e-5f);
    float v0 = (e0 - m) * inv * sc[t]       + bi[t];
    float v1 = (e1 - m) * inv * sc[t + 256] + bi[t + 256];
    float v2 = (e2 - m) * inv * sc[t + 512] + bi[t + 512];
    if (outB) {
        short* o = outB + (size_t)row * D;
        o[t] = f2b(v0); o[t + 256] = f2b(v1); o[t + 512] = f2b(v2);
    } else {
        float* o = outF + (size_t)row * D;
        o[t] = v0; o[t + 256] = v1; o[t + 512] = v2;
    }
}

// ---------------------------------------------------------------------------
// bf16 MFMA GEMM, BM x BN tile, BK=32, swizzle chunk ^= (r>>1)&3 both-sides.
// Depth-2 pipeline: 3 LDS buffers, counted vmcnt + raw s_barrier.
// NFAST: tile decode N-fastest within XCD chunk (A row-tile L2 reuse);
// else M-fastest (W panel reuse). gx = count of the FAST dimension.
// ---------------------------------------------------------------------------
template<int BM, int BN, bool NFAST>
__global__ __launch_bounds__(256) void gemm2(
    const short* __restrict__ A, const short* __restrict__ Wt,
    const float* __restrict__ Bb0, const float* __restrict__ Bb1, const float* __restrict__ Bb2,
    float* __restrict__ outF, const float* __restrict__ resid,
    short* __restrict__ outB,
    int K, int nper, int gx, float alpha0, int mode)
{
    constexpr int MR = BM / 32;
    constexpr int NR = BN / 32;
    constexpr int NL = BM / 64 + BN / 64;    // per-thread global_load_lds per tile
    __shared__ __align__(16) short As[3][BM * 32];
    __shared__ __align__(16) short Bs[3][BN * 32];
    int tid  = threadIdx.x;
    int lane = tid & 63;
    int w    = tid >> 6;

    int nwg = gridDim.x;
    int bid = blockIdx.x;
    int sid = (bid & 7) * (nwg >> 3) + (bid >> 3);
    int row0, n0;
    if (NFAST) { row0 = (sid / gx) * BM; n0 = (sid % gx) * BN; }
    else       { row0 = (sid % gx) * BM; n0 = (sid / gx) * BN; }

    int which = n0 / nper;
    int ncol0 = n0 - which * nper;
    const float* Bv = (which == 0) ? Bb0 : ((which == 1) ? Bb1 : Bb2);
    float alpha = (which == 0) ? alpha0 : 1.0f;

    int wr = (w >> 1) * (BM / 2);
    int wc = (w & 1) * (BN / 2);
    int fr = lane & 15;
    int q4 = lane >> 4;          // 0..3 (16B chunk within 64B row)

    f32x4 acc[MR][NR] = {};

    auto stageA = [&](int buf, int k0) {
        #pragma unroll
        for (int ii = 0; ii < BM / 64; ++ii) {
            int U = ii * 256 + tid;          // 16B unit
            int r = U >> 2;
            int ch = (U & 3) ^ ((r >> 1) & 3);
            gload16(A + (size_t)(row0 + r) * K + k0 + ch * 8,
                    (char*)&As[buf][0] + ((size_t)ii * 256 + w * 64) * 16);
        }
    };
    auto stageB = [&](int buf, int k0) {
        #pragma unroll
        for (int ii = 0; ii < BN / 64; ++ii) {
            int U = ii * 256 + tid;
            int r = U >> 2;
            int ch = (U & 3) ^ ((r >> 1) & 3);
            gload16(Wt + (size_t)(n0 + r) * K + k0 + ch * 8,
                    (char*)&Bs[buf][0] + ((size_t)ii * 256 + w * 64) * 16);
        }
    };
    auto compute = [&](int buf) {
        bf16x8 af[MR], bfr[NR];
        #pragma unroll
        for (int m = 0; m < MR; ++m) {
            int r = wr + m * 16 + fr;
            af[m] = *(const bf16x8*)((const char*)&As[buf][0]
                    + (size_t)r * 64 + ((q4 ^ ((r >> 1) & 3)) * 16));
        }
        #pragma unroll
        for (int n = 0; n < NR; ++n) {
            int r = wc + n * 16 + fr;
            bfr[n] = *(const bf16x8*)((const char*)&Bs[buf][0]
                    + (size_t)r * 64 + ((q4 ^ ((r >> 1) & 3)) * 16));
        }
        #pragma unroll
        for (int m = 0; m < MR; ++m)
            #pragma unroll
            for (int n = 0; n < NR; ++n)
                acc[m][n] = __builtin_amdgcn_mfma_f32_16x16x32_bf16(af[m], bfr[n], acc[m][n], 0, 0, 0);
    };

    int nt = K >> 5;
    stageA(0, 0); stageB(0, 0);
    stageA(1, 32); stageB(1, 32);
    for (int t = 0; t < nt - 1; ++t) {
        asm volatile("s_waitcnt vmcnt(%0)" :: "i"(NL) : "memory");   // tile t landed
        __builtin_amdgcn_sched_barrier(0);
        __builtin_amdgcn_s_barrier();
        if (t + 2 < nt) {
            int b2 = (t + 2) % 3;
            stageA(b2, (t + 2) * 32);
            stageB(b2, (t + 2) * 32);
        }
        compute(t % 3);
    }
    asm volatile("s_waitcnt vmcnt(0)" ::: "memory");
    __builtin_amdgcn_sched_barrier(0);
    __builtin_amdgcn_s_barrier();
    compute((nt - 1) % 3);

    int rr = q4 * 4;
    if (mode == 1) {
        short* base = outB + (size_t)which * ROWS * D;
        #pragma unroll
        for (int m = 0; m < MR; ++m) {
            int rowb = row0 + wr + m * 16 + rr;
            int b2 = rowb >> 9, s0 = rowb & 511;
            #pragma unroll
            for (int n = 0; n < NR; ++n) {
                int col = ncol0 + wc + n * 16 + fr;
                int h2 = col >> 6, d2 = col & 63;
                float bv = Bv[col];
                if (which == 2) {
                    bf16x4 pk;
                    #pragma unroll
                    for (int ri = 0; ri < 4; ++ri) pk[ri] = f2b(acc[m][n][ri] + bv);
                    *(bf16x4*)&base[(((size_t)b2 * H + h2) * 64 + d2) * 512 + s0] = pk;
                } else {
                    #pragma unroll
                    for (int ri = 0; ri < 4; ++ri)
                        base[(((size_t)b2 * H + h2) * 512 + (s0 + ri)) * 64 + d2] =
                            f2b((acc[m][n][ri] + bv) * alpha);
                }
            }
        }
        return;
    }

    #pragma unroll
    for (int m = 0; m < MR; ++m) {
        #pragma unroll
        for (int n = 0; n < NR; ++n) {
            int col  = ncol0 + wc + n * 16 + fr;
            float bv = Bv[col];
            #pragma unroll
            for (int ri = 0; ri < 4; ++ri) {
                int row = row0 + wr + m * 16 + rr + ri;
                size_t idx = (size_t)row * nper + col;
                float val = acc[m][n][ri] + bv;
                if (mode == 2) {
                    outB[idx] = f2b(gelu_f(val));
                } else {
                    outF[idx] = val + resid[idx];
                }
            }
        }
    }
}

// ---------------------------------------------------------------------------
// LDS-staged online-softmax attention (round-10, verified).
// ---------------------------------------------------------------------------
__global__ __launch_bounds__(256) void attn_kernel(
    const short* __restrict__ qb, const short* __restrict__ kbuf,
    const short* __restrict__ vtb,
    const uint32_t* __restrict__ pb,
    const float* __restrict__ vd, const float* __restrict__ ac,
    short* __restrict__ o)
{
    __shared__ __align__(16) short Ks[2][128 * 64];
    __shared__ __align__(16) short Vs[2][64 * 128];
    int tid = threadIdx.x, lane = tid & 63, w = tid >> 6;
    int bid = blockIdx.x;
    int b    = bid & 7;
    int qblk = (bid >> 3) & 7;
    int hh   = bid >> 6;
    int fr = lane & 15, g16 = lane >> 4;
    int kb8 = g16 * 8, rr = g16 * 4;
    int i0 = qblk * 64 + w * 16;
    int i  = i0 + fr;

    const short* qp = qb   + ((size_t)(b * H + hh) * S) * 64;
    const short* kp = kbuf + ((size_t)(b * H + hh) * S) * 64;
    const short* vp = vtb  + ((size_t)(b * H + hh) * 64) * S;

    bf16x8 aq0 = *(const bf16x8*)&qp[(i0 + fr) * 64 + kb8];
    bf16x8 aq1 = *(const bf16x8*)&qp[(i0 + fr) * 64 + 32 + kb8];

    float Ah = ac[hh], Ch = ac[16 + hh], th = vd[hh];
    const uint32_t* pbb = pb + (size_t)b * S * S + (size_t)i * S;

    auto stageK = [&](int buf, int j0) {
        #pragma unroll
        for (int ii = 0; ii < 4; ++ii) {
            int U = ii * 256 + tid;
            int r = U >> 3;
            int ch = (U & 7) ^ (r & 7);
            gload16(kp + (size_t)(j0 + r) * 64 + ch * 8,
                    (char*)&Ks[buf][0] + ((size_t)ii * 256 + w * 64) * 16);
        }
    };
    auto stageV = [&](int buf, int j0) {
        #pragma unroll
        for (int ii = 0; ii < 4; ++ii) {
            int U = ii * 256 + tid;
            int d = U >> 4;
            int s8 = (2 * (U & 15)) ^ (d & 14);
            gload16(vp + (size_t)d * S + j0 + s8 * 4,
                    (char*)&Vs[buf][0] + ((size_t)ii * 256 + w * 64) * 16);
        }
    };

    float m_run = -3.0e38f, l_run = 0.f;
    f32x4 oacc[4] = {};

    stageK(0, 0);
    stageV(0, 0);
    __syncthreads();
    int buf = 0;
    #pragma unroll 1
    for (int t = 0; t < 4; ++t) {
        if (t < 3) { stageK(buf ^ 1, (t + 1) * 128); stageV(buf ^ 1, (t + 1) * 128); }
        f32x4 s[8];
        #pragma unroll
        for (int jt = 0; jt < 8; ++jt) {
            int jb = t * 8 + jt;
            u32x4 u = *(const u32x4*)&pbb[jb * 16 + rr];
            f32x4 c;
            #pragma unroll
            for (int ri = 0; ri < 4; ++ri) {
                int j = jb * 16 + rr + ri;
                float bias = b2f_lo(u[ri]);
                if (i > 0 && j > 0) bias += b2f_hi(u[ri]) * Ah + Ch;
                if (i == 0 || j == 0) bias += th;
                c[ri] = bias;
            }
            int r = jt * 16 + fr;
            const char* krow = (const char*)&Ks[buf][0] + r * 128;
            bf16x8 kf0 = *(const bf16x8*)(krow + ((g16 ^ (r & 7)) * 16));
            bf16x8 kf1 = *(const bf16x8*)(krow + (((g16 + 4) ^ (r & 7)) * 16));
            c = __builtin_amdgcn_mfma_f32_16x16x32_bf16(kf0, aq0, c, 0, 0, 0);
            s[jt] = __builtin_amdgcn_mfma_f32_16x16x32_bf16(kf1, aq1, c, 0, 0, 0);
        }
        float tm = s[0][0];
        #pragma unroll
        for (int jt = 0; jt < 8; ++jt)
            #pragma unroll
            for (int ri = 0; ri < 4; ++ri) tm = fmaxf(tm, s[jt][ri]);
        tm = fmaxf(tm, __shfl_xor(tm, 16));
        tm = fmaxf(tm, __shfl_xor(tm, 32));
        float mnew = fmaxf(m_run, tm);
        float scale = __expf(m_run - mnew);
        l_run *= scale;
        #pragma unroll
        for (int ri = 0; ri < 4; ++ri) {
            float scr = __shfl(scale, rr + ri);
            #pragma unroll
            for (int dt = 0; dt < 4; ++dt) oacc[dt][ri] *= scr;
        }
        #pragma unroll
        for (int jt = 0; jt < 8; ++jt)
            #pragma unroll
            for (int ri = 0; ri < 4; ++ri) {
                float p = __expf(s[jt][ri] - mnew);
                s[jt][ri] = p;
                l_run += p;
            }
        #pragma unroll
        for (int jt = 0; jt < 8; ++jt) {
            bf16x4 pa;
            #pragma unroll
            for (int ri = 0; ri < 4; ++ri) pa[ri] = f2b(s[jt][ri]);
            #pragma unroll
            for (int dt = 0; dt < 4; ++dt) {
                int d = dt * 16 + fr;
                const char* vrow = (const char*)&Vs[buf][0] + d * 256;
                bf16x4 vb = *(const bf16x4*)(vrow + (((jt * 4 + g16) ^ (d & 14)) * 8));
                oacc[dt] = mfma16(pa, vb, oacc[dt]);
            }
        }
        m_run = mnew;
        __syncthreads();
        buf ^= 1;
    }
    mfma16_fence(oacc);

    l_run += __shfl_xor(l_run, 16);
    l_run += __shfl_xor(l_run, 32);
    float invl = 1.f / l_run;
    #pragma unroll
    for (int ri = 0; ri < 4; ++ri) {
        float ivr = __shfl(invl, rr + ri);
        #pragma unroll
        for (int dt = 0; dt < 4; ++dt)
            o[((size_t)(b * S + i0 + rr + ri) * H + hh) * 64 + dt * 16 + fr] =
                f2b(oacc[dt][ri] * ivr);
    }
}

// ---------------------------------------------------------------------------
extern "C" void kernel_launch(void* const* d_in, const int* in_sizes, int n_in,
                              void* d_out, int out_size, void* d_ws, size_t ws_size,
                              hipStream_t stream)
{
    const float* attn_bias   = (const float*)d_in[0];
    const float* spatial_pos = (const float*)d_in[1];
    const int*   xx          = (const int*)d_in[2];
    const float* node_emb    = (const float*)d_in[3];
    const float* graph_token = (const float*)d_in[4];
    const float* virt_dist   = (const float*)d_in[5];
    const float* sp_w1 = (const float*)d_in[6];
    const float* sp_b1 = (const float*)d_in[7];
    const float* sp_w2 = (const float*)d_in[8];
    const float* sp_b2 = (const float*)d_in[9];
    const float* ln1_s = (const float*)d_in[10];
    const float* ln1_b = (const float*)d_in[11];
    const float* wq = (const float*)d_in[12];
    const float* bq = (const float*)d_in[13];
    const float* wk = (const float*)d_in[14];
    const float* bk = (const float*)d_in[15];
    const float* wv = (const float*)d_in[16];
    const float* bv = (const float*)d_in[17];
    const float* wo = (const float*)d_in[18];
    const float* bo = (const float*)d_in[19];
    const float* ln2_s = (const float*)d_in[20];
    const float* ln2_b = (const float*)d_in[21];
    const float* fw1 = (const float*)d_in[22];
    const float* fb1 = (const float*)d_in[23];
    const float* fw2 = (const float*)d_in[24];
    const float* fb2 = (const float*)d_in[25];
    const float* fln_s = (const float*)d_in[26];
    const float* fln_b = (const float*)d_in[27];

    float* wsf = (float*)d_ws;
    const size_t SZ = (size_t)ROWS * D;        // 3,145,728
    float* h   = wsf;                          // f32 [ROWS][D]
    float* acb = wsf + SZ;                     // A[12],C[12]
    short* s16 = (short*)(wsf + SZ + 64);
    short* yob = s16;                          // bf16 [ROWS][D]
    short* g16b = s16 + SZ;                    // bf16 [ROWS][FFN]
    short* bfq = g16b + (size_t)ROWS * FFN;    // 3 x bf16 [ROWS*D]
    short* wqkvT = bfq + 3 * SZ;               // [2304][768]
    short* woT   = wqkvT + 2304 * 768;         // [768][768]
    short* f1T   = woT + 768 * 768;            // [3072][768]
    short* f2T   = f1T + (size_t)3072 * 768;   // [768][3072]
    uint32_t* pbias = (uint32_t*)(f2T + (size_t)768 * 3072);  // [B][S][S] u32

    embed_kernel<<<ROWS, 256, 0, stream>>>(xx, node_emb, graph_token, h);
    ac_kernel<<<1, 64, 0, stream>>>(sp_w1, sp_b1, sp_w2, sp_b2, acb);
    bias_pack_kernel<<<ROWS, 256, 0, stream>>>(attn_bias, spatial_pos, pbias);

    for (int l = 0; l < 6; ++l) {
        wcvt_kernel<<<1728, 256, 0, stream>>>(
            wq + (size_t)l * D * D, wk + (size_t)l * D * D, wv + (size_t)l * D * D,
            wo + (size_t)l * D * D, fw1 + (size_t)l * D * FFN, fw2 + (size_t)l * FFN * D,
            wqkvT, woT, f1T, f2T);
        ln_kernel<<<ROWS, 256, 0, stream>>>(h, ln1_s + l * D, ln1_b + l * D, nullptr, yob);
        gemm2<128, 128, false><<<576, 256, 0, stream>>>(
            yob, wqkvT, bq + l * D, bk + l * D, bv + l * D,
            nullptr, nullptr, bfq, D, D, 32, 0.125f, 1);
        attn_kernel<<<B * H * 8, 256, 0, stream>>>(
            bfq, bfq + SZ, bfq + 2 * SZ, pbias, virt_dist, acb, yob);
        // o-proj: 64x64 tiles, N-fastest (A-reuse); gx = 12 N-tiles
        gemm2<64, 64, true><<<768, 256, 0, stream>>>(
            yob, woT, bo + l * D, nullptr, nullptr,
            h, h, nullptr, D, D, 12, 1.0f, 0);
        ln_kernel<<<ROWS, 256, 0, stream>>>(h, ln2_s + l * D, ln2_b + l * D, nullptr, yob);
        gemm2<128, 128, false><<<768, 256, 0, stream>>>(
            yob, f1T, fb1 + l * FFN, nullptr, nullptr,
            nullptr, nullptr, g16b, D, FFN, 32, 1.0f, 2);
        // FFN2: 64x64 tiles, N-fastest (A-reuse); gx = 12 N-tiles
        gemm2<64, 64, true><<<768, 256, 0, stream>>>(
            g16b, f2T, fb2 + l * D, nullptr, nullptr,
            h, h, nullptr, FFN, D, 12, 1.0f, 0);
    }
    ln_kernel<<<ROWS, 256, 0, stream>>>(h, fln_s, fln_b, (float*)d_out, nullptr);
}

// Round 18
// 1025.839 us; speedup vs baseline: 1.3930x; 1.0926x over previous
//
#include <hip/hip_runtime.h>
#include <cstdint>
#include <cstddef>

// ---------------------------------------------------------------------------
// Graphormer-ish encoder forward, MI355X (gfx950).
// Round 17: BK=64 for the 64x64-tile GEMMs (FFN2, o-proj): 3 bufs x 16KB =
// 48KB LDS -> 3 blocks/CU capacity == the grid's 3 blocks/CU (no residency
// loss, unlike round-11's 128-tile attempt), barrier count halves, MFMA per
// barrier doubles. Swizzle for 128B rows: chunk ^= (r&7) both-sides
// (round-11 verified). QKV/FFN1 unchanged (BK=32, 128x128).
// ---------------------------------------------------------------------------

typedef __attribute__((ext_vector_type(8))) short bf16x8;
typedef __attribute__((ext_vector_type(4))) short bf16x4;
typedef __attribute__((ext_vector_type(4))) float f32x4;
typedef __attribute__((ext_vector_type(4))) unsigned int u32x4;

static constexpr int D    = 768;
static constexpr int H    = 12;
static constexpr int S    = 512;
static constexpr int NN   = 511;
static constexpr int B    = 8;
static constexpr int FFN  = 3072;
static constexpr int ROWS = B * S;   // 4096

__device__ __forceinline__ short f2b(float x) {
    union { float f; uint32_t u; } c; c.f = x;
    uint32_t r = (c.u + 0x7fffu + ((c.u >> 16) & 1u)) >> 16;  // RNE
    return (short)(uint16_t)r;
}
__device__ __forceinline__ float b2f_lo(uint32_t u) {
    union { uint32_t u; float f; } c; c.u = u << 16; return c.f;
}
__device__ __forceinline__ float b2f_hi(uint32_t u) {
    union { uint32_t u; float f; } c; c.u = u & 0xffff0000u; return c.f;
}
__device__ __forceinline__ float gelu_f(float x) {
    return 0.5f * x * (1.0f + erff(x * 0.7071067811865476f));
}
__device__ __forceinline__ void gload16(const void* g, void* l) {
    __builtin_amdgcn_global_load_lds(
        (const __attribute__((address_space(1))) void*)g,
        (__attribute__((address_space(3))) void*)l, 16, 0, 0);
}

// PV MFMA: 16x16x16 bf16 (builtin -> compiler handles MFMA hazards).
#if __has_builtin(__builtin_amdgcn_mfma_f32_16x16x16bf16_1k)
__device__ __forceinline__ f32x4 mfma16(bf16x4 a, bf16x4 b, f32x4 c) {
    return __builtin_amdgcn_mfma_f32_16x16x16bf16_1k(a, b, c, 0, 0, 0);
}
__device__ __forceinline__ void mfma16_fence(f32x4* o) { (void)o; }
#else
__device__ __forceinline__ f32x4 mfma16(bf16x4 a, bf16x4 b, f32x4 c) {
    asm volatile("s_nop 1\n\tv_mfma_f32_16x16x16_bf16 %0, %1, %2, %0"
                 : "+v"(c) : "v"(a), "v"(b));
    return c;
}
__device__ __forceinline__ void mfma16_fence(f32x4* o) {
    asm volatile("s_nop 7\n\ts_nop 7"
                 : "+v"(o[0]), "+v"(o[1]), "+v"(o[2]), "+v"(o[3]));
}
#endif

// ---------------------------------------------------------------------------
__global__ __launch_bounds__(256) void embed_kernel(
    const int* __restrict__ x, const float* __restrict__ emb,
    const float* __restrict__ gtok, float* __restrict__ h)
{
    int row = blockIdx.x;
    int b = row >> 9, s = row & (S - 1);
    const float* src = (s == 0) ? gtok : (emb + (size_t)x[b * NN + (s - 1)] * D);
    float* dst = h + (size_t)row * D;
    int t = threadIdx.x;
    dst[t]       = src[t];
    dst[t + 256] = src[t + 256];
    dst[t + 512] = src[t + 512];
}

// ---------------------------------------------------------------------------
__global__ void ac_kernel(const float* __restrict__ w1, const float* __restrict__ b1,
                          const float* __restrict__ w2, const float* __restrict__ b2,
                          float* __restrict__ ac)
{
    int h = threadIdx.x;
    if (h < H) {
        float a = 0.f, c = 0.f;
        for (int k = 0; k < 128; ++k) { a += w1[k] * w2[k * H + h]; c += b1[k] * w2[k * H + h]; }
        ac[h] = a; ac[16 + h] = c + b2[h];
    }
}

// ---------------------------------------------------------------------------
// Bias pack, [b][i][j] layout: pb[b,i,j] = u32( bf16(2*ab) | bf16(sp)<<16 )
// ---------------------------------------------------------------------------
__global__ __launch_bounds__(256) void bias_pack_kernel(
    const float* __restrict__ ab, const float* __restrict__ sp,
    uint32_t* __restrict__ pb)
{
    int row = blockIdx.x;                 // b*S + i
    int b = row >> 9, i = row & 511;
    const float* abr = ab + (size_t)row * S;
    const float* spr = sp + ((size_t)b * NN + (i - 1)) * NN;
    uint32_t* out = pb + (size_t)row * S;
    #pragma unroll
    for (int jt = 0; jt < 2; ++jt) {
        int j = jt * 256 + threadIdx.x;
        float a2 = 2.f * abr[j];
        float spv = (i > 0 && j > 0) ? spr[j - 1] : 0.f;
        out[j] = (uint32_t)(uint16_t)f2b(a2) | ((uint32_t)(uint16_t)f2b(spv) << 16);
    }
}

// ---------------------------------------------------------------------------
// Per-layer weight convert+transpose: f32 [R][C] -> bf16 [C][R].
// ---------------------------------------------------------------------------
__global__ __launch_bounds__(256) void wcvt_kernel(
    const float* __restrict__ wq, const float* __restrict__ wk,
    const float* __restrict__ wv, const float* __restrict__ wo,
    const float* __restrict__ f1, const float* __restrict__ f2,
    short* __restrict__ wqkvT, short* __restrict__ woT,
    short* __restrict__ f1T, short* __restrict__ f2T)
{
    int t = blockIdx.x;
    const float* in; short* out; int R, C, tr, tc;
    if (t < 432) {
        int which = t / 144, tt = t - which * 144;
        in = (which == 0) ? wq : ((which == 1) ? wk : wv);
        out = wqkvT + (size_t)which * 768 * 768;
        R = 768; C = 768; tr = tt / 12; tc = tt % 12;
    } else if (t < 576) {
        int tt = t - 432; in = wo; out = woT; R = 768; C = 768; tr = tt / 12; tc = tt % 12;
    } else if (t < 1152) {
        int tt = t - 576; in = f1; out = f1T; R = 768; C = 3072; tr = tt / 48; tc = tt % 48;
    } else {
        int tt = t - 1152; in = f2; out = f2T; R = 3072; C = 768; tr = tt / 12; tc = tt % 12;
    }
    int r0 = tr * 64, c0 = tc * 64;
    __shared__ short tile[64][65];
    int tid = threadIdx.x;
    #pragma unroll
    for (int i = 0; i < 16; ++i) {
        int e = i * 256 + tid; int r = e >> 6, c = e & 63;
        tile[r][c] = f2b(in[(size_t)(r0 + r) * C + c0 + c]);
    }
    __syncthreads();
    #pragma unroll
    for (int i = 0; i < 16; ++i) {
        int e = i * 256 + tid; int c = e >> 6, r = e & 63;
        out[(size_t)(c0 + c) * R + r0 + r] = tile[r][c];
    }
}

// ---------------------------------------------------------------------------
__global__ __launch_bounds__(256) void ln_kernel(
    const float* __restrict__ in, const float* __restrict__ sc,
    const float* __restrict__ bi, float* __restrict__ outF,
    short* __restrict__ outB)
{
    int row = blockIdx.x, t = threadIdx.x;
    const float* x = in + (size_t)row * D;
    float e0 = x[t], e1 = x[t + 256], e2 = x[t + 512];
    float s  = e0 + e1 + e2;
    float sq = e0 * e0 + e1 * e1 + e2 * e2;
    #pragma unroll
    for (int off = 1; off < 64; off <<= 1) { s += __shfl_xor(s, off); sq += __shfl_xor(sq, off); }
    __shared__ float red[8];
    int w = t >> 6, lane = t & 63;
    if (lane == 0) { red[w] = s; red[4 + w] = sq; }
    __syncthreads();
    s  = red[0] + red[1] + red[2] + red[3];
    sq = red[4] + red[5] + red[6] + red[7];
    float m   = s * (1.f / D);
    float inv = rsqrtf(sq * (1.f / D) - m * m + 1e-5f);
    float v0 = (e0 - m) * inv * sc[t]       + bi[t];
    float v1 = (e1 - m) * inv * sc[t + 256] + bi[t + 256];
    float v2 = (e2 - m) * inv * sc[t + 512] + bi[t + 512];
    if (outB) {
        short* o = outB + (size_t)row * D;
        o[t] = f2b(v0); o[t + 256] = f2b(v1); o[t + 512] = f2b(v2);
    } else {
        float* o = outF + (size_t)row * D;
        o[t] = v0; o[t + 256] = v1; o[t + 512] = v2;
    }
}

// ---------------------------------------------------------------------------
// bf16 MFMA GEMM, BM x BN x BK tile, depth-2 pipeline (3 LDS bufs, counted
// vmcnt + raw s_barrier). Swizzle both-sides: BK=32 rows (64B, 4 chunks):
// chunk ^= (r>>1)&3; BK=64 rows (128B, 8 chunks): chunk ^= r&7.
// NFAST: tile decode N-fastest within XCD chunk.
// ---------------------------------------------------------------------------
template<int BM, int BN, int BK, bool NFAST>
__global__ __launch_bounds__(256) void gemm2(
    const short* __restrict__ A, const short* __restrict__ Wt,
    const float* __restrict__ Bb0, const float* __restrict__ Bb1, const float* __restrict__ Bb2,
    float* __restrict__ outF, const float* __restrict__ resid,
    short* __restrict__ outB,
    int K, int nper, int gx, float alpha0, int mode)
{
    constexpr int MR = BM / 32;
    constexpr int NR = BN / 32;
    constexpr int SUBK = BK / 32;
    constexpr int AU = BM * BK / 2048;       // stage iters for A
    constexpr int BU = BN * BK / 2048;
    constexpr int CH = BK / 8;               // 16B chunks per row
    constexpr int NL = AU + BU;              // per-thread loads per tile
    __shared__ __align__(16) short As[3][BM * BK];
    __shared__ __align__(16) short Bs[3][BN * BK];
    int tid  = threadIdx.x;
    int lane = tid & 63;
    int w    = tid >> 6;

    int nwg = gridDim.x;
    int bid = blockIdx.x;
    int sid = (bid & 7) * (nwg >> 3) + (bid >> 3);
    int row0, n0;
    if (NFAST) { row0 = (sid / gx) * BM; n0 = (sid % gx) * BN; }
    else       { row0 = (sid % gx) * BM; n0 = (sid / gx) * BN; }

    int which = n0 / nper;
    int ncol0 = n0 - which * nper;
    const float* Bv = (which == 0) ? Bb0 : ((which == 1) ? Bb1 : Bb2);
    float alpha = (which == 0) ? alpha0 : 1.0f;

    int wr = (w >> 1) * (BM / 2);
    int wc = (w & 1) * (BN / 2);
    int fr = lane & 15;
    int q4 = lane >> 4;          // 0..3

    auto swz = [&](int r) -> int { return (BK == 64) ? (r & 7) : ((r >> 1) & 3); };

    f32x4 acc[MR][NR] = {};

    auto stageA = [&](int buf, int k0) {
        #pragma unroll
        for (int ii = 0; ii < AU; ++ii) {
            int U = ii * 256 + tid;          // 16B unit
            int r = U / CH;
            int ch = (U % CH) ^ swz(r);
            gload16(A + (size_t)(row0 + r) * K + k0 + ch * 8,
                    (char*)&As[buf][0] + ((size_t)ii * 256 + w * 64) * 16);
        }
    };
    auto stageB = [&](int buf, int k0) {
        #pragma unroll
        for (int ii = 0; ii < BU; ++ii) {
            int U = ii * 256 + tid;
            int r = U / CH;
            int ch = (U % CH) ^ swz(r);
            gload16(Wt + (size_t)(n0 + r) * K + k0 + ch * 8,
                    (char*)&Bs[buf][0] + ((size_t)ii * 256 + w * 64) * 16);
        }
    };
    auto compute = [&](int buf) {
        #pragma unroll
        for (int s = 0; s < SUBK; ++s) {
            bf16x8 af[MR], bfr[NR];
            #pragma unroll
            for (int m = 0; m < MR; ++m) {
                int r = wr + m * 16 + fr;
                af[m] = *(const bf16x8*)((const char*)&As[buf][0]
                        + (size_t)r * (2 * BK) + (((q4 + 4 * s) ^ swz(r)) * 16));
            }
            #pragma unroll
            for (int n = 0; n < NR; ++n) {
                int r = wc + n * 16 + fr;
                bfr[n] = *(const bf16x8*)((const char*)&Bs[buf][0]
                        + (size_t)r * (2 * BK) + (((q4 + 4 * s) ^ swz(r)) * 16));
            }
            #pragma unroll
            for (int m = 0; m < MR; ++m)
                #pragma unroll
                for (int n = 0; n < NR; ++n)
                    acc[m][n] = __builtin_amdgcn_mfma_f32_16x16x32_bf16(af[m], bfr[n], acc[m][n], 0, 0, 0);
        }
    };

    int nt = K / BK;
    stageA(0, 0); stageB(0, 0);
    stageA(1, BK); stageB(1, BK);
    for (int t = 0; t < nt - 1; ++t) {
        asm volatile("s_waitcnt vmcnt(%0)" :: "i"(NL) : "memory");   // tile t landed
        __builtin_amdgcn_sched_barrier(0);
        __builtin_amdgcn_s_barrier();
        if (t + 2 < nt) {
            int b2 = (t + 2) % 3;
            stageA(b2, (t + 2) * BK);
            stageB(b2, (t + 2) * BK);
        }
        compute(t % 3);
    }
    asm volatile("s_waitcnt vmcnt(0)" ::: "memory");
    __builtin_amdgcn_sched_barrier(0);
    __builtin_amdgcn_s_barrier();
    compute((nt - 1) % 3);

    int rr = q4 * 4;
    if (mode == 1) {
        short* base = outB + (size_t)which * ROWS * D;
        #pragma unroll
        for (int m = 0; m < MR; ++m) {
            int rowb = row0 + wr + m * 16 + rr;
            int b2 = rowb >> 9, s0 = rowb & 511;
            #pragma unroll
            for (int n = 0; n < NR; ++n) {
                int col = ncol0 + wc + n * 16 + fr;
                int h2 = col >> 6, d2 = col & 63;
                float bv = Bv[col];
                if (which == 2) {
                    bf16x4 pk;
                    #pragma unroll
                    for (int ri = 0; ri < 4; ++ri) pk[ri] = f2b(acc[m][n][ri] + bv);
                    *(bf16x4*)&base[(((size_t)b2 * H + h2) * 64 + d2) * 512 + s0] = pk;
                } else {
                    #pragma unroll
                    for (int ri = 0; ri < 4; ++ri)
                        base[(((size_t)b2 * H + h2) * 512 + (s0 + ri)) * 64 + d2] =
                            f2b((acc[m][n][ri] + bv) * alpha);
                }
            }
        }
        return;
    }

    #pragma unroll
    for (int m = 0; m < MR; ++m) {
        #pragma unroll
        for (int n = 0; n < NR; ++n) {
            int col  = ncol0 + wc + n * 16 + fr;
            float bv = Bv[col];
            #pragma unroll
            for (int ri = 0; ri < 4; ++ri) {
                int row = row0 + wr + m * 16 + rr + ri;
                size_t idx = (size_t)row * nper + col;
                float val = acc[m][n][ri] + bv;
                if (mode == 2) {
                    outB[idx] = f2b(gelu_f(val));
                } else {
                    outF[idx] = val + resid[idx];
                }
            }
        }
    }
}

// ---------------------------------------------------------------------------
// LDS-staged online-softmax attention (round-10, verified).
// ---------------------------------------------------------------------------
__global__ __launch_bounds__(256) void attn_kernel(
    const short* __restrict__ qb, const short* __restrict__ kbuf,
    const short* __restrict__ vtb,
    const uint32_t* __restrict__ pb,
    const float* __restrict__ vd, const float* __restrict__ ac,
    short* __restrict__ o)
{
    __shared__ __align__(16) short Ks[2][128 * 64];
    __shared__ __align__(16) short Vs[2][64 * 128];
    int tid = threadIdx.x, lane = tid & 63, w = tid >> 6;
    int bid = blockIdx.x;
    int b    = bid & 7;
    int qblk = (bid >> 3) & 7;
    int hh   = bid >> 6;
    int fr = lane & 15, g16 = lane >> 4;
    int kb8 = g16 * 8, rr = g16 * 4;
    int i0 = qblk * 64 + w * 16;
    int i  = i0 + fr;

    const short* qp = qb   + ((size_t)(b * H + hh) * S) * 64;
    const short* kp = kbuf + ((size_t)(b * H + hh) * S) * 64;
    const short* vp = vtb  + ((size_t)(b * H + hh) * 64) * S;

    bf16x8 aq0 = *(const bf16x8*)&qp[(i0 + fr) * 64 + kb8];
    bf16x8 aq1 = *(const bf16x8*)&qp[(i0 + fr) * 64 + 32 + kb8];

    float Ah = ac[hh], Ch = ac[16 + hh], th = vd[hh];
    const uint32_t* pbb = pb + (size_t)b * S * S + (size_t)i * S;

    auto stageK = [&](int buf, int j0) {
        #pragma unroll
        for (int ii = 0; ii < 4; ++ii) {
            int U = ii * 256 + tid;
            int r = U >> 3;
            int ch = (U & 7) ^ (r & 7);
            gload16(kp + (size_t)(j0 + r) * 64 + ch * 8,
                    (char*)&Ks[buf][0] + ((size_t)ii * 256 + w * 64) * 16);
        }
    };
    auto stageV = [&](int buf, int j0) {
        #pragma unroll
        for (int ii = 0; ii < 4; ++ii) {
            int U = ii * 256 + tid;
            int d = U >> 4;
            int s8 = (2 * (U & 15)) ^ (d & 14);
            gload16(vp + (size_t)d * S + j0 + s8 * 4,
                    (char*)&Vs[buf][0] + ((size_t)ii * 256 + w * 64) * 16);
        }
    };

    float m_run = -3.0e38f, l_run = 0.f;
    f32x4 oacc[4] = {};

    stageK(0, 0);
    stageV(0, 0);
    __syncthreads();
    int buf = 0;
    #pragma unroll 1
    for (int t = 0; t < 4; ++t) {
        if (t < 3) { stageK(buf ^ 1, (t + 1) * 128); stageV(buf ^ 1, (t + 1) * 128); }
        f32x4 s[8];
        #pragma unroll
        for (int jt = 0; jt < 8; ++jt) {
            int jb = t * 8 + jt;
            u32x4 u = *(const u32x4*)&pbb[jb * 16 + rr];
            f32x4 c;
            #pragma unroll
            for (int ri = 0; ri < 4; ++ri) {
                int j = jb * 16 + rr + ri;
                float bias = b2f_lo(u[ri]);
                if (i > 0 && j > 0) bias += b2f_hi(u[ri]) * Ah + Ch;
                if (i == 0 || j == 0) bias += th;
                c[ri] = bias;
            }
            int r = jt * 16 + fr;
            const char* krow = (const char*)&Ks[buf][0] + r * 128;
            bf16x8 kf0 = *(const bf16x8*)(krow + ((g16 ^ (r & 7)) * 16));
            bf16x8 kf1 = *(const bf16x8*)(krow + (((g16 + 4) ^ (r & 7)) * 16));
            c = __builtin_amdgcn_mfma_f32_16x16x32_bf16(kf0, aq0, c, 0, 0, 0);
            s[jt] = __builtin_amdgcn_mfma_f32_16x16x32_bf16(kf1, aq1, c, 0, 0, 0);
        }
        float tm = s[0][0];
        #pragma unroll
        for (int jt = 0; jt < 8; ++jt)
            #pragma unroll
            for (int ri = 0; ri < 4; ++ri) tm = fmaxf(tm, s[jt][ri]);
        tm = fmaxf(tm, __shfl_xor(tm, 16));
        tm = fmaxf(tm, __shfl_xor(tm, 32));
        float mnew = fmaxf(m_run, tm);
        float scale = __expf(m_run - mnew);
        l_run *= scale;
        #pragma unroll
        for (int ri = 0; ri < 4; ++ri) {
            float scr = __shfl(scale, rr + ri);
            #pragma unroll
            for (int dt = 0; dt < 4; ++dt) oacc[dt][ri] *= scr;
        }
        #pragma unroll
        for (int jt = 0; jt < 8; ++jt)
            #pragma unroll
            for (int ri = 0; ri < 4; ++ri) {
                float p = __expf(s[jt][ri] - mnew);
                s[jt][ri] = p;
                l_run += p;
            }
        #pragma unroll
        for (int jt = 0; jt < 8; ++jt) {
            bf16x4 pa;
            #pragma unroll
            for (int ri = 0; ri < 4; ++ri) pa[ri] = f2b(s[jt][ri]);
            #pragma unroll
            for (int dt = 0; dt < 4; ++dt) {
                int d = dt * 16 + fr;
                const char* vrow = (const char*)&Vs[buf][0] + d * 256;
                bf16x4 vb = *(const bf16x4*)(vrow + (((jt * 4 + g16) ^ (d & 14)) * 8));
                oacc[dt] = mfma16(pa, vb, oacc[dt]);
            }
        }
        m_run = mnew;
        __syncthreads();
        buf ^= 1;
    }
    mfma16_fence(oacc);

    l_run += __shfl_xor(l_run, 16);
    l_run += __shfl_xor(l_run, 32);
    float invl = 1.f / l_run;
    #pragma unroll
    for (int ri = 0; ri < 4; ++ri) {
        float ivr = __shfl(invl, rr + ri);
        #pragma unroll
        for (int dt = 0; dt < 4; ++dt)
            o[((size_t)(b * S + i0 + rr + ri) * H + hh) * 64 + dt * 16 + fr] =
                f2b(oacc[dt][ri] * ivr);
    }
}

// ---------------------------------------------------------------------------
extern "C" void kernel_launch(void* const* d_in, const int* in_sizes, int n_in,
                              void* d_out, int out_size, void* d_ws, size_t ws_size,
                              hipStream_t stream)
{
    const float* attn_bias   = (const float*)d_in[0];
    const float* spatial_pos = (const float*)d_in[1];
    const int*   xx          = (const int*)d_in[2];
    const float* node_emb    = (const float*)d_in[3];
    const float* graph_token = (const float*)d_in[4];
    const float* virt_dist   = (const float*)d_in[5];
    const float* sp_w1 = (const float*)d_in[6];
    const float* sp_b1 = (const float*)d_in[7];
    const float* sp_w2 = (const float*)d_in[8];
    const float* sp_b2 = (const float*)d_in[9];
    const float* ln1_s = (const float*)d_in[10];
    const float* ln1_b = (const float*)d_in[11];
    const float* wq = (const float*)d_in[12];
    const float* bq = (const float*)d_in[13];
    const float* wk = (const float*)d_in[14];
    const float* bk = (const float*)d_in[15];
    const float* wv = (const float*)d_in[16];
    const float* bv = (const float*)d_in[17];
    const float* wo = (const float*)d_in[18];
    const float* bo = (const float*)d_in[19];
    const float* ln2_s = (const float*)d_in[20];
    const float* ln2_b = (const float*)d_in[21];
    const float* fw1 = (const float*)d_in[22];
    const float* fb1 = (const float*)d_in[23];
    const float* fw2 = (const float*)d_in[24];
    const float* fb2 = (const float*)d_in[25];
    const float* fln_s = (const float*)d_in[26];
    const float* fln_b = (const float*)d_in[27];

    float* wsf = (float*)d_ws;
    const size_t SZ = (size_t)ROWS * D;        // 3,145,728
    float* h   = wsf;                          // f32 [ROWS][D]
    float* acb = wsf + SZ;                     // A[12],C[12]
    short* s16 = (short*)(wsf + SZ + 64);
    short* yob = s16;                          // bf16 [ROWS][D]
    short* g16b = s16 + SZ;                    // bf16 [ROWS][FFN]
    short* bfq = g16b + (size_t)ROWS * FFN;    // 3 x bf16 [ROWS*D]
    short* wqkvT = bfq + 3 * SZ;               // [2304][768]
    short* woT   = wqkvT + 2304 * 768;         // [768][768]
    short* f1T   = woT + 768 * 768;            // [3072][768]
    short* f2T   = f1T + (size_t)3072 * 768;   // [768][3072]
    uint32_t* pbias = (uint32_t*)(f2T + (size_t)768 * 3072);  // [B][S][S] u32

    embed_kernel<<<ROWS, 256, 0, stream>>>(xx, node_emb, graph_token, h);
    ac_kernel<<<1, 64, 0, stream>>>(sp_w1, sp_b1, sp_w2, sp_b2, acb);
    bias_pack_kernel<<<ROWS, 256, 0, stream>>>(attn_bias, spatial_pos, pbias);

    for (int l = 0; l < 6; ++l) {
        wcvt_kernel<<<1728, 256, 0, stream>>>(
            wq + (size_t)l * D * D, wk + (size_t)l * D * D, wv + (size_t)l * D * D,
            wo + (size_t)l * D * D, fw1 + (size_t)l * D * FFN, fw2 + (size_t)l * FFN * D,
            wqkvT, woT, f1T, f2T);
        ln_kernel<<<ROWS, 256, 0, stream>>>(h, ln1_s + l * D, ln1_b + l * D, nullptr, yob);
        gemm2<128, 128, 32, false><<<576, 256, 0, stream>>>(
            yob, wqkvT, bq + l * D, bk + l * D, bv + l * D,
            nullptr, nullptr, bfq, D, D, 32, 0.125f, 1);
        attn_kernel<<<B * H * 8, 256, 0, stream>>>(
            bfq, bfq + SZ, bfq + 2 * SZ, pbias, virt_dist, acb, yob);
        // o-proj: 64x64 tiles, BK=64, N-fastest; 12 K-steps
        gemm2<64, 64, 64, true><<<768, 256, 0, stream>>>(
            yob, woT, bo + l * D, nullptr, nullptr,
            h, h, nullptr, D, D, 12, 1.0f, 0);
        ln_kernel<<<ROWS, 256, 0, stream>>>(h, ln2_s + l * D, ln2_b + l * D, nullptr, yob);
        gemm2<128, 128, 32, false><<<768, 256, 0, stream>>>(
            yob, f1T, fb1 + l * FFN, nullptr, nullptr,
            nullptr, nullptr, g16b, D, FFN, 32, 1.0f, 2);
        // FFN2: 64x64 tiles, BK=64, N-fastest; 48 K-steps
        gemm2<64, 64, 64, true><<<768, 256, 0, stream>>>(
            g16b, f2T, fb2 + l * D, nullptr, nullptr,
            h, h, nullptr, FFN, D, 12, 1.0f, 0);
    }
    ln_kernel<<<ROWS, 256, 0, stream>>>(h, fln_s, fln_b, (float*)d_out, nullptr);
}